// Round 8
// baseline (403.719 us; speedup 1.0000x reference)
//
#include <hip/hip_runtime.h>

// ---------- constants ----------
#define HID 2048
#define NH 16
#define QLR 1536
#define KVLR 512
#define DN 128
#define DR 64
#define DV 128
#define BB 2
#define SS 2048
#define NTOK (BB*SS)   // 4096
#define QD 3072        // H*(DN+DR)
#define KVD 4096       // H*(DN+DV)
#define CKVD 576       // DR+KVLR
#define NQT2 (SS/128)  // 16 q-tiles of 128

typedef __bf16 bf16x8 __attribute__((ext_vector_type(8)));
typedef float f32x4 __attribute__((ext_vector_type(4)));
typedef float f32x16 __attribute__((ext_vector_type(16)));
typedef unsigned short us4v __attribute__((ext_vector_type(4)));
typedef unsigned int u32x4 __attribute__((ext_vector_type(4)));

__device__ __forceinline__ unsigned short f2bf(float f){
  unsigned u = __builtin_bit_cast(unsigned, f);
  return (unsigned short)((u + 0x7fffu + ((u>>16)&1u)) >> 16);
}
__device__ __forceinline__ float bf2f(unsigned short h){
  unsigned u = ((unsigned)h)<<16; return __builtin_bit_cast(float, u);
}
__device__ __forceinline__ unsigned cvt_pk_bf16(float a, float b){
  unsigned r;
  asm("v_cvt_pk_bf16_f32 %0, %1, %2" : "=v"(r) : "v"(a), "v"(b));
  return r;
}

#define GLOAD16(g, l) __builtin_amdgcn_global_load_lds( \
    (const __attribute__((address_space(1))) void*)(const void*)(g), \
    (__attribute__((address_space(3))) void*)(void*)(l), 16, 0, 0)

// ---------- fp32 -> bf16 convert (vectorized) ----------
__global__ void cvt_f32_bf16(const float* __restrict__ in, unsigned short* __restrict__ out, int n4){
  int i = blockIdx.x*256 + threadIdx.x;
  if (i < n4){
    float4 v = ((const float4*)in)[i];
    us4v o = { f2bf(v.x), f2bf(v.y), f2bf(v.z), f2bf(v.w) };
    ((us4v*)out)[i] = o;
  }
}

// ---------- weight transpose + convert: W[K][N] f32 -> WT[Npad][K] bf16 ----------
__global__ void wtrans(const float* __restrict__ W, unsigned short* __restrict__ WT,
                       int K, int N){
  __shared__ float t[32][33];
  int n0 = blockIdx.x*32, k0 = blockIdx.y*32;
  int tx = threadIdx.x & 31, ty = threadIdx.x >> 5;
  #pragma unroll
  for (int i = ty; i < 32; i += 8){
    int k = k0 + i, n = n0 + tx;
    t[i][tx] = (n < N) ? W[(size_t)k*N + n] : 0.f;
  }
  __syncthreads();
  #pragma unroll
  for (int i = ty; i < 32; i += 8){
    int n = n0 + i, k = k0 + tx;
    WT[(size_t)n*K + k] = f2bf(t[tx][i]);
  }
}

// ---------- bf16 GEMM core: C[M][N] = A[M][K] @ BT[N][K]^T + bias ----------
template<bool OUTF32>
__device__ __forceinline__ void gemm_core(
  unsigned short* As, unsigned short* Bs,
  const unsigned short* __restrict__ A, int lda,
  const unsigned short* __restrict__ BT,
  const float* __restrict__ bias,
  void* __restrict__ Cv, int ldc,
  int N, int K, int bx, int by)
{
  const int tid = threadIdx.x;
  const int wave = tid>>6, lane = tid&63, lq = lane&15, lg = lane>>4;
  const int tm = by*128, tn = bx*128;
  const int wm = (wave>>1)*64, wn = (wave&1)*64;
  f32x4 acc[4][4] = {};
  char* AsB = (char*)As; char* BsB = (char*)Bs;
  const int r8 = tid>>3;                 // row within 32-row group
  const int sc = ((tid&7) ^ (r8&7))*8;   // swizzled source col (shorts)
  for (int kt = 0; kt < K; kt += 64){
    __syncthreads();
    #pragma unroll
    for (int rd=0; rd<4; rd++){
      GLOAD16(A  + (size_t)(tm + rd*32 + r8)*lda + kt + sc, AsB + rd*4096 + wave*1024);
      GLOAD16(BT + (size_t)(tn + rd*32 + r8)*K   + kt + sc, BsB + rd*4096 + wave*1024);
    }
    asm volatile("s_waitcnt vmcnt(0)" ::: "memory");
    __syncthreads();
    #pragma unroll
    for (int h=0; h<2; h++){
      bf16x8 af[4], bfr[4];
      #pragma unroll
      for (int i=0;i<4;i++) af[i]  = *(const bf16x8*)(AsB + (wm+16*i+lq)*128 + ((((h*4+lg)^(lq&7)))<<4));
      #pragma unroll
      for (int j=0;j<4;j++) bfr[j] = *(const bf16x8*)(BsB + (wn+16*j+lq)*128 + ((((h*4+lg)^(lq&7)))<<4));
      #pragma unroll
      for (int i=0;i<4;i++)
        #pragma unroll
        for (int j=0;j<4;j++)
          acc[i][j] = __builtin_amdgcn_mfma_f32_16x16x32_bf16(af[i], bfr[j], acc[i][j], 0,0,0);
    }
  }
  #pragma unroll
  for (int i=0;i<4;i++){
    #pragma unroll
    for (int j=0;j<4;j++){
      int col = tn + wn + 16*j + lq;
      if (col < N){
        float bv = bias ? bias[col] : 0.f;
        #pragma unroll
        for (int r=0;r<4;r++){
          int row = tm + wm + 16*i + lg*4 + r;
          float v = acc[i][j][r] + bv;
          if (OUTF32) ((float*)Cv)[(size_t)row*ldc + col] = v;
          else ((unsigned short*)Cv)[(size_t)row*ldc + col] = f2bf(v);
        }
      }
    }
  }
}

// XCD-chunked bijective remap (requires nwg % 8 == 0 — all our grids comply)
__device__ __forceinline__ void xcd_remap(int& bx, int& by){
  int nwg = gridDim.x*gridDim.y;
  int lin = blockIdx.y*gridDim.x + blockIdx.x;
  int wg = (lin&7)*(nwg>>3) + (lin>>3);
  bx = wg % gridDim.x; by = wg / gridDim.x;
}

template<bool OUTF32>
__global__ __launch_bounds__(256) void gemm_bt(
  const unsigned short* __restrict__ A, int lda,
  const unsigned short* __restrict__ BT,
  const float* __restrict__ bias,
  void* __restrict__ Cv, int ldc, int N, int K)
{
  __shared__ unsigned short As[128*64];
  __shared__ unsigned short Bs[128*64];
  int bx, by; xcd_remap(bx, by);
  gemm_core<OUTF32>(As, Bs, A, lda, BT, bias, Cv, ldc, N, K, bx, by);
}

__global__ __launch_bounds__(256) void gemm_bt_dual(
  const unsigned short* __restrict__ A0, int lda0, const unsigned short* __restrict__ BT0,
  const float* __restrict__ b0, void* __restrict__ C0, int ldc0, int N0, int K0,
  const unsigned short* __restrict__ A1, int lda1, const unsigned short* __restrict__ BT1,
  const float* __restrict__ b1, void* __restrict__ C1, int ldc1, int N1, int K1,
  int split)
{
  __shared__ unsigned short As[128*64];
  __shared__ unsigned short Bs[128*64];
  int bx, by; xcd_remap(bx, by);
  if (bx < split)
    gemm_core<false>(As, Bs, A0, lda0, BT0, b0, C0, ldc0, N0, K0, bx, by);
  else
    gemm_core<false>(As, Bs, A1, lda1, BT1, b1, C1, ldc1, N1, K1, bx - split, by);
}

// ---------- fused: rmsnorm(cq), rmsnorm(ckv), rope_k ----------
__device__ __forceinline__ void rms_row(unsigned short* x, int D, float* red){
  int tid = threadIdx.x;
  float ss = 0.f;
  for (int i = tid; i < D; i += 256){ float v = bf2f(x[i]); ss += v*v; }
  #pragma unroll
  for (int o=32;o;o>>=1) ss += __shfl_xor(ss, o, 64);
  if ((tid&63)==0) red[tid>>6] = ss;
  __syncthreads();
  float tot = red[0]+red[1]+red[2]+red[3];
  float sc = rsqrtf(tot/(float)D + 1e-6f);
  for (int i = tid; i < D; i += 256) x[i] = f2bf(bf2f(x[i])*sc);
}

__global__ void norms_fused(unsigned short* __restrict__ cq,
                            unsigned short* __restrict__ ckv,
                            unsigned short* __restrict__ kr){
  __shared__ float red[4];
  int bid = blockIdx.x;
  if (bid < NTOK){
    rms_row(cq + (size_t)bid*QLR, QLR, red);
  } else if (bid < 2*NTOK){
    rms_row(ckv + (size_t)(bid-NTOK)*CKVD + DR, KVLR, red);
  } else {
    int idx = (bid - 2*NTOK)*256 + threadIdx.x;
    int j = idx & 31;
    int t = idx >> 5;
    int s = t & (SS-1);
    const unsigned short* src = ckv + (size_t)t*CKVD;
    float xr = bf2f(src[j]), xi = bf2f(src[j+32]);
    float freq = powf(10000.f, -(float)(2*j)/64.f);
    float ang = (float)s * freq;
    float c = cosf(ang), sn = sinf(ang);
    kr[(size_t)t*64 + j]      = f2bf(xr*c - xi*sn);
    kr[(size_t)t*64 + j + 32] = f2bf(xi*c + xr*sn);
  }
}

// ---------- fused: rope_q (in-place) + V transpose ----------
__global__ void ropeq_vt_fused(unsigned short* __restrict__ q,
                               const unsigned short* __restrict__ kv,
                               unsigned short* __restrict__ vT){
  int bid = blockIdx.x;
  if (bid < NTOK*NH*32/256){
    int idx = bid*256 + threadIdx.x;   // B*S*H*32
    int j = idx & 31;
    int h = (idx >> 5) & 15;
    int t = idx >> 9;            // token
    int s = t & (SS-1);
    unsigned short* base = q + (size_t)t*QD + h*(DN+DR) + DN;
    float xr = bf2f(base[j]), xi = bf2f(base[j+32]);
    float freq = powf(10000.f, -(float)(2*j)/64.f);
    float ang = (float)s * freq;
    float c = cosf(ang), sn = sinf(ang);
    base[j]    = f2bf(xr*c - xi*sn);
    base[j+32] = f2bf(xi*c + xr*sn);
  } else {
    __shared__ unsigned short t[32][33];
    int idx = bid - NTOK*NH*32/256;    // 8192 tiles: (s0i 64, d0i 4, bh 32)
    int s0 = (idx & 63)*32, d0 = ((idx>>6)&3)*32, bh = idx>>8;
    int b = bh>>4, h = bh&15;
    int tx = threadIdx.x & 31, ty = threadIdx.x >> 5;
    #pragma unroll
    for (int i = ty; i < 32; i += 8)
      t[i][tx] = kv[((size_t)(b*SS + s0+i))*KVD + h*(DN+DV) + DN + d0 + tx];
    __syncthreads();
    #pragma unroll
    for (int i = ty; i < 32; i += 8)
      vT[((size_t)(bh*DV + d0+i))*SS + s0 + tx] = t[tx][i];
  }
}

// ---------- causal flash attention (32x32x16, key-segment split) ----------
// 896 blocks. lin decode: bh=(lin&7)+8*((lin>>3)&3) (XCD-grouped),
// rest=lin>>5 in steps-descending order:
//   rest<24: split tile  qt=15-(rest>>1), seg=rest&1, 2qt+2 steps each
//   rest>=24: whole tile qt=27-rest (3..0), 4qt+4 steps
// Split blocks store NORMALIZED O (bf16) + (m,l) into dead-workspace pools;
// attn_combine merges the two segments. This halves the longest block's
// serial chain (64->32 steps) and raises resident blocks/CU to 3 — round-7
// showed ~27% exposed-latency idle at 2 blocks/CU with the tail pinned by
// the 64-step blocks.
__global__ __launch_bounds__(256) void attn_kernel(
  const unsigned short* __restrict__ q,   // [NTOK][3072] rope-applied
  const unsigned short* __restrict__ kv,  // [NTOK][4096]
  const unsigned short* __restrict__ kr,  // [NTOK][64] roped
  const unsigned short* __restrict__ vT,  // [32][128][S]
  unsigned short* __restrict__ attn,      // [NTOK][2048]
  unsigned short* __restrict__ OpA,       // partial pool A (448 tiles)
  unsigned short* __restrict__ OpC,       // partial pool C (320 tiles)
  float2* __restrict__ mlp)               // [768][128] (m, l)
{
  __shared__ unsigned short Ksn[2][32*128];  // 8 KB each
  __shared__ unsigned short Ksr[2][32*64];   // 4 KB each
  __shared__ unsigned short Vs [2][128*32];  // 8 KB each
  __shared__ unsigned short Ps [4*32*36];    // per-wave 32 rows x 72 B
  const int tid = threadIdx.x, wave = tid>>6, lane = tid&63;
  const int lo = lane&31, hi = lane>>5;
  const int lin = blockIdx.x;
  const int bh = (lin&7) + 8*((lin>>3)&3);
  const int rest = lin>>5;
  int qt, k0, nseg, pidx = 0;
  if (rest < 24){
    qt = 15 - (rest>>1);
    int seg = rest & 1;
    nseg = 2*qt + 2;
    k0 = seg ? nseg : 0;
    pidx = ((rest>>1)*32 + bh)*2 + seg;
  } else {
    qt = 27 - rest;          // 3..0
    nseg = 4*qt + 4;
    k0 = 0;
  }
  const int b = bh>>4, h = bh&15;
  const float kmul = 1.44269504f * 0.07216878364f; // log2e / sqrt(192)

  // staging pointers (advance per 32-key step), pre-advanced to k0
  const int rK = tid>>4, cK = (tid&15) ^ (rK&7);
  const int rR = tid>>3, cR = (tid&7) ^ (rR&7);
  const int rV = tid>>2, cV = (tid&3) ^ (rV&3);
  const unsigned short* pKn0 = kv + (size_t)(b*SS + k0*32 + rK)*KVD + h*(DN+DV) + cK*8;
  const unsigned short* pKn1 = pKn0 + (size_t)16*KVD;
  const unsigned short* pKr  = kr + (size_t)(b*SS + k0*32 + rR)*64 + cR*8;
  const unsigned short* pV0  = vT + ((size_t)bh*DV + rV)*SS + k0*32 + cV*8;
  const unsigned short* pV1  = pV0 + (size_t)64*SS;

#define STAGE_ATTN(bufi) do {                                                 \
    GLOAD16(pKn0, (char*)Ksn[bufi] +        wave*1024);                       \
    GLOAD16(pKn1, (char*)Ksn[bufi] + 4096 + wave*1024);                       \
    GLOAD16(pKr,  (char*)Ksr[bufi] +        wave*1024);                       \
    GLOAD16(pV0,  (char*)Vs[bufi]  +        wave*1024);                       \
    GLOAD16(pV1,  (char*)Vs[bufi]  + 4096 + wave*1024);                       \
    pKn0 += 32*KVD; pKn1 += 32*KVD; pKr += 32*64; pV0 += 32; pV1 += 32;       \
  } while(0)

  const int qw = qt*128 + wave*32;
  const int myq = qw + lo;
  // Q fragments: lane holds q-row (qw+lo), k = c*16 + hi*8 .. +7
  bf16x8 qf[12];
  {
    const unsigned short* qrow = q + (size_t)(b*SS + myq)*QD + h*(DN+DR);
    #pragma unroll
    for (int c=0;c<12;c++) qf[c] = *(const bf16x8*)(qrow + c*16 + hi*8);
  }
  f32x16 oacc[4] = {};
  float m = -1e30f, lsum = 0.f;
  const int kend = k0 + nseg;

  STAGE_ATTN(0);
  asm volatile("s_waitcnt vmcnt(0)" ::: "memory");
  __builtin_amdgcn_s_barrier();
  int cur = 0;
  for (int kt = k0; kt < kend; kt++){
    if (kt+1 < kend) STAGE_ATTN(cur^1);
    // ---- QK^T: S^T[key=32][q=32], A = K-tile rows, B = Q regs ----
    f32x16 sacc = {};
    __builtin_amdgcn_s_setprio(1);
    #pragma unroll
    for (int ck=0;ck<8;ck++){
      bf16x8 kf = *(const bf16x8*)((char*)Ksn[cur] + lo*256 + ((((ck*2+hi)^(lo&7)))<<4));
      sacc = __builtin_amdgcn_mfma_f32_32x32x16_bf16(kf, qf[ck], sacc, 0,0,0);
    }
    #pragma unroll
    for (int ck=0;ck<4;ck++){
      bf16x8 kf = *(const bf16x8*)((char*)Ksr[cur] + lo*128 + ((((ck*2+hi)^(lo&7)))<<4));
      sacc = __builtin_amdgcn_mfma_f32_32x32x16_bf16(kf, qf[8+ck], sacc, 0,0,0);
    }
    __builtin_amdgcn_s_setprio(0);
    // ---- online softmax: key-row(r) = (r&3)+8*(r>>2)+4*hi, q-col = lo ----
    float s[16]; float pmax = -1e30f;
    if (kt*32 + 31 <= qw){
      #pragma unroll
      for (int r=0;r<16;r++){ float v = sacc[r]*kmul; s[r]=v; pmax=fmaxf(pmax,v); }
    } else {
      #pragma unroll
      for (int r=0;r<16;r++){
        int kpos = kt*32 + (r&3) + 8*(r>>2) + 4*hi;
        float v = (kpos <= myq) ? sacc[r]*kmul : -1e30f;
        s[r]=v; pmax=fmaxf(pmax,v);
      }
    }
    pmax = fmaxf(pmax, __shfl_xor(pmax, 32, 64));
    if (!__all(pmax <= m + 8.f)){   // defer-max
      float mnew = fmaxf(m, pmax);
      float alpha = __builtin_amdgcn_exp2f(m - mnew);
      m = mnew; lsum *= alpha;
      #pragma unroll
      for (int dt=0;dt<4;dt++)
        #pragma unroll
        for (int r=0;r<16;r++) oacc[dt][r] *= alpha;
    }
    float psum = 0.f;
    #pragma unroll
    for (int r=0;r<16;r++){ s[r] = __builtin_amdgcn_exp2f(s[r] - m); psum += s[r]; }
    psum += __shfl_xor(psum, 32, 64);
    lsum += psum;
    // ---- P -> per-wave padded LDS tile, then B-fragments ----
    unsigned short* Pw = Ps + wave*32*36;
    #pragma unroll
    for (int rg=0; rg<4; rg++){
      uint2 pk = { cvt_pk_bf16(s[rg*4+0], s[rg*4+1]),
                   cvt_pk_bf16(s[rg*4+2], s[rg*4+3]) };
      *(uint2*)((char*)Pw + lo*72 + rg*16 + hi*8) = pk;
    }
    bf16x8 pf[2];
    #pragma unroll
    for (int j=0;j<2;j++){
      uint2 a0 = *(const uint2*)((char*)Pw + lo*72 + (2*j+hi)*16);
      uint2 a1 = *(const uint2*)((char*)Pw + lo*72 + (2*j+hi)*16 + 8);
      u32x4 pk4 = { a0.x, a0.y, a1.x, a1.y };
      pf[j] = __builtin_bit_cast(bf16x8, pk4);
    }
    // ---- PV: O[d=32][q=32] per d-tile, A = V^T rows, B = pf ----
    __builtin_amdgcn_s_setprio(1);
    #pragma unroll
    for (int dt=0; dt<4; dt++){
      const int row = dt*32 + lo;
      #pragma unroll
      for (int j=0;j<2;j++){
        bf16x8 vf = *(const bf16x8*)((char*)Vs[cur] + row*64 + ((((j*2+hi)^(lo&3)))<<4));
        oacc[dt] = __builtin_amdgcn_mfma_f32_32x32x16_bf16(vf, pf[j], oacc[dt], 0,0,0);
      }
    }
    __builtin_amdgcn_s_setprio(0);
    asm volatile("s_waitcnt vmcnt(0)" ::: "memory");
    __builtin_amdgcn_s_barrier();
    cur ^= 1;
  }
  // ---- epilogue: O rows d = (r&3)+8*(r>>2)+4*hi+32*dt, col q = lo ----
  float inv = 1.f / lsum;
  if (rest < 24){
    // normalized partial -> pool; (m,l) -> mlp
    unsigned short* Op = (pidx < 448) ? OpA + (size_t)pidx*16384
                                      : OpC + (size_t)(pidx-448)*16384;
    const int prow = wave*32 + lo;
    #pragma unroll
    for (int dt=0; dt<4; dt++){
      #pragma unroll
      for (int rq=0; rq<4; rq++){
        int dbase = dt*32 + rq*8 + hi*4;
        uint2 o = { cvt_pk_bf16(oacc[dt][rq*4+0]*inv, oacc[dt][rq*4+1]*inv),
                    cvt_pk_bf16(oacc[dt][rq*4+2]*inv, oacc[dt][rq*4+3]*inv) };
        *(uint2*)(Op + prow*128 + dbase) = o;
      }
    }
    if (hi == 0) mlp[(size_t)pidx*128 + prow] = make_float2(m, lsum);
  } else {
    unsigned short* orow = attn + (size_t)(b*SS + myq)*2048 + h*DV;
    #pragma unroll
    for (int dt=0; dt<4; dt++){
      #pragma unroll
      for (int rq=0; rq<4; rq++){
        int dbase = dt*32 + rq*8 + hi*4;
        uint2 o = { cvt_pk_bf16(oacc[dt][rq*4+0]*inv, oacc[dt][rq*4+1]*inv),
                    cvt_pk_bf16(oacc[dt][rq*4+2]*inv, oacc[dt][rq*4+3]*inv) };
        *(uint2*)(orow + dbase) = o;
      }
    }
  }
#undef STAGE_ATTN
}

// ---------- combine two key-segments: out = (w0*O0 + w1*O1), w = l*2^(m-M) ----------
__global__ __launch_bounds__(256) void attn_combine(
  const unsigned short* __restrict__ OpA, const unsigned short* __restrict__ OpC,
  const float2* __restrict__ mlp, unsigned short* __restrict__ attn)
{
  int pair = blockIdx.x;             // 0..383 = (15-qt)*32 + bh
  int qt = 15 - (pair >> 5);
  int bh = pair & 31;
  int b = bh>>4, h = bh&15;
  int t = threadIdx.x;
  int row = t >> 1, dh = (t&1)*64;
  int p0 = pair*2, p1 = pair*2 + 1;
  const unsigned short* O0 = ((p0 < 448) ? OpA + (size_t)p0*16384 : OpC + (size_t)(p0-448)*16384) + row*128 + dh;
  const unsigned short* O1 = ((p1 < 448) ? OpA + (size_t)p1*16384 : OpC + (size_t)(p1-448)*16384) + row*128 + dh;
  float2 a = mlp[(size_t)p0*128 + row];
  float2 c = mlp[(size_t)p1*128 + row];
  float M = fmaxf(a.x, c.x);
  float w0 = a.y * __builtin_amdgcn_exp2f(a.x - M);
  float w1 = c.y * __builtin_amdgcn_exp2f(c.x - M);
  float inv = 1.f / (w0 + w1);
  w0 *= inv; w1 *= inv;
  unsigned short* dst = attn + (size_t)(b*SS + qt*128 + row)*2048 + h*DV + dh;
  #pragma unroll
  for (int i = 0; i < 64; i += 8){
    u32x4 v0 = *(const u32x4*)(O0 + i);
    u32x4 v1 = *(const u32x4*)(O1 + i);
    const unsigned short* s0 = (const unsigned short*)&v0;
    const unsigned short* s1 = (const unsigned short*)&v1;
    float f[8];
    #pragma unroll
    for (int j=0;j<8;j++) f[j] = bf2f(s0[j])*w0 + bf2f(s1[j])*w1;
    u32x4 o = { cvt_pk_bf16(f[0],f[1]), cvt_pk_bf16(f[2],f[3]),
                cvt_pk_bf16(f[4],f[5]), cvt_pk_bf16(f[6],f[7]) };
    *(u32x4*)(dst + i) = o;
  }
}

// ---------- launch ----------
extern "C" void kernel_launch(void* const* d_in, const int* in_sizes, int n_in,
                              void* d_out, int out_size, void* d_ws, size_t ws_size,
                              hipStream_t stream){
  const float* X    = (const float*)d_in[0];
  const float* Wqd  = (const float*)d_in[2];
  const float* bqd  = (const float*)d_in[3];
  const float* Wqu  = (const float*)d_in[4];
  const float* bqu  = (const float*)d_in[5];
  const float* Wkvd = (const float*)d_in[6];
  const float* bkvd = (const float*)d_in[7];
  const float* Wkvu = (const float*)d_in[8];
  const float* bkvu = (const float*)d_in[9];
  const float* Wo   = (const float*)d_in[10];
  const float* bo   = (const float*)d_in[11];
  float* out = (float*)d_out;

  char* ws = (char*)d_ws;
  // workspace layout (bytes); attn output overlays Xb (dead after G1G3).
  // During attn: arena + cq + ckv are dead -> partial pools (OpA/OpC/mlp).
  unsigned short* Xb    = (unsigned short*)(ws + 0);          // 16,777,216
  unsigned short* attnb = (unsigned short*)(ws + 0);
  char*           arena = ws + 16777216;                      // weight arena (14,680,064)
  unsigned short* Wt1 = (unsigned short*)(arena);             // 1536x2048x2 = 6,291,456
  unsigned short* Wt3 = (unsigned short*)(arena + 6291456);   // 640x2048x2  = 2,621,440
  unsigned short* Wt2 = (unsigned short*)(arena);             // 3072x1536x2 = 9,437,184
  unsigned short* Wt4 = (unsigned short*)(arena + 9437184);   // 4096x512x2  = 4,194,304
  unsigned short* Wt5 = (unsigned short*)(arena);             // 2048x2048x2 = 8,388,608
  unsigned short* cq   = (unsigned short*)(ws + 31457280);    // 12,582,912
  unsigned short* qtmp = (unsigned short*)(ws + 44040192);    // 25,165,824
  unsigned short* ckv  = (unsigned short*)(ws + 69206016);    //  4,718,592
  unsigned short* kvt  = (unsigned short*)(ws + 73924608);    // 33,554,432
  unsigned short* kr   = (unsigned short*)(ws + 107479040);   //    524,288
  unsigned short* vT   = (unsigned short*)(ws + 108003328);   // 16,777,216  (end 124,780,544)
  // attn partial pools (live only attn..combine; overlap arena/cq/ckv):
  unsigned short* OpA  = (unsigned short*)(arena);            // 448 * 32,768 B = 14,680,064
  unsigned short* OpC  = (unsigned short*)(ws + 31457280);    // 320 * 32,768 B <= 12,582,912
  float2*         mlp  = (float2*)(ws + 69206016);            // 768*128*8 = 786,432

  // 1. X -> bf16
  cvt_f32_bf16<<<dim3(NTOK*HID/4/256), 256, 0, stream>>>(X, Xb, NTOK*HID/4);
  // 2. W transposes for down-projections, fused G1+G3
  wtrans<<<dim3(QLR/32, HID/32), 256, 0, stream>>>(Wqd, Wt1, HID, QLR);
  wtrans<<<dim3(640/32, HID/32), 256, 0, stream>>>(Wkvd, Wt3, HID, CKVD);
  gemm_bt_dual<<<dim3(QLR/128 + 640/128, NTOK/128), 256, 0, stream>>>(
      Xb, HID, Wt1, bqd, cq, QLR, QLR, HID,
      Xb, HID, Wt3, bkvd, ckv, CKVD, CKVD, HID, QLR/128);
  // 3. norms + k rope (fused)
  norms_fused<<<dim3(2*NTOK + NTOK*32/256), 256, 0, stream>>>(cq, ckv, kr);
  // 4. W transposes for up-projections, fused G2+G4
  wtrans<<<dim3(QD/32, QLR/32), 256, 0, stream>>>(Wqu, Wt2, QLR, QD);
  wtrans<<<dim3(KVD/32, KVLR/32), 256, 0, stream>>>(Wkvu, Wt4, KVLR, KVD);
  gemm_bt_dual<<<dim3(QD/128 + KVD/128, NTOK/128), 256, 0, stream>>>(
      cq, QLR, Wt2, bqu, qtmp, QD, QD, QLR,
      ckv + DR, CKVD, Wt4, bkvu, kvt, KVD, KVD, KVLR, QD/128);
  // 5. q rope + V^T (fused)
  ropeq_vt_fused<<<dim3(NTOK*NH*32/256 + 8192), 256, 0, stream>>>(qtmp, kvt, vT);
  // 6. attention (896 blocks: split long tiles along keys) + combine
  attn_kernel<<<dim3(896), 256, 0, stream>>>(qtmp, kvt, kr, vT, attnb, OpA, OpC, mlp);
  attn_combine<<<dim3(384), 256, 0, stream>>>(OpA, OpC, mlp, attnb);
  // 7. Wo^T ; GEMM5 -> out (f32)
  wtrans<<<dim3(HID/32, HID/32), 256, 0, stream>>>(Wo, Wt5, HID, HID);
  gemm_bt<true><<<dim3(HID/128, NTOK/128), 256, 0, stream>>>(attnb, HID, Wt5, bo, out, HID, HID, HID);
}

// Round 9
// 390.224 us; speedup vs baseline: 1.0346x; 1.0346x over previous
//
#include <hip/hip_runtime.h>

// ---------- constants ----------
#define HID 2048
#define NH 16
#define QLR 1536
#define KVLR 512
#define DN 128
#define DR 64
#define DV 128
#define BB 2
#define SS 2048
#define NTOK (BB*SS)   // 4096
#define QD 3072        // H*(DN+DR)
#define KVD 4096       // H*(DN+DV)
#define CKVD 576       // DR+KVLR
#define NQT2 (SS/128)  // 16 q-tiles of 128

typedef __bf16 bf16x8 __attribute__((ext_vector_type(8)));
typedef float f32x4 __attribute__((ext_vector_type(4)));
typedef float f32x16 __attribute__((ext_vector_type(16)));
typedef unsigned short us4v __attribute__((ext_vector_type(4)));
typedef unsigned int u32x4 __attribute__((ext_vector_type(4)));

__device__ __forceinline__ unsigned short f2bf(float f){
  unsigned u = __builtin_bit_cast(unsigned, f);
  return (unsigned short)((u + 0x7fffu + ((u>>16)&1u)) >> 16);
}
__device__ __forceinline__ float bf2f(unsigned short h){
  unsigned u = ((unsigned)h)<<16; return __builtin_bit_cast(float, u);
}
__device__ __forceinline__ unsigned cvt_pk_bf16(float a, float b){
  unsigned r;
  asm("v_cvt_pk_bf16_f32 %0, %1, %2" : "=v"(r) : "v"(a), "v"(b));
  return r;
}

#define GLOAD16(g, l) __builtin_amdgcn_global_load_lds( \
    (const __attribute__((address_space(1))) void*)(const void*)(g), \
    (__attribute__((address_space(3))) void*)(void*)(l), 16, 0, 0)

// ---------- fp32 -> bf16 convert (vectorized) ----------
__global__ void cvt_f32_bf16(const float* __restrict__ in, unsigned short* __restrict__ out, int n4){
  int i = blockIdx.x*256 + threadIdx.x;
  if (i < n4){
    float4 v = ((const float4*)in)[i];
    us4v o = { f2bf(v.x), f2bf(v.y), f2bf(v.z), f2bf(v.w) };
    ((us4v*)out)[i] = o;
  }
}

// ---------- weight transpose + convert: W[K][N] f32 -> WT[Npad][K] bf16 ----------
__global__ void wtrans(const float* __restrict__ W, unsigned short* __restrict__ WT,
                       int K, int N){
  __shared__ float t[32][33];
  int n0 = blockIdx.x*32, k0 = blockIdx.y*32;
  int tx = threadIdx.x & 31, ty = threadIdx.x >> 5;
  #pragma unroll
  for (int i = ty; i < 32; i += 8){
    int k = k0 + i, n = n0 + tx;
    t[i][tx] = (n < N) ? W[(size_t)k*N + n] : 0.f;
  }
  __syncthreads();
  #pragma unroll
  for (int i = ty; i < 32; i += 8){
    int n = n0 + i, k = k0 + tx;
    WT[(size_t)n*K + k] = f2bf(t[tx][i]);
  }
}

// ---------- bf16 GEMM core: C[M][N] = A[M][K] @ BT[N][K]^T + bias ----------
// 128x128 tile, 4 waves, 16x16x32 MFMA. 3-BUFFER / BK=32 COUNTED-VMCNT
// PIPELINE: stage K-tile t+2 into buffer (t+2)%3 while computing t;
// s_waitcnt vmcnt(4) (t+2's 4 loads stay in flight) + raw s_barrier —
// never drains to 0 in steady state, so staging HBM latency is hidden
// across barriers (removes the ~20% vmcnt(0)-drain stall of the old
// __syncthreads 2-phase loop). LDS 48KB -> 3 blocks/CU.
// Chunk swizzle c ^= (row^(row>>2))&3 (involutive on pre-swizzled global
// source + read address; <=2-way bank residue = free).
template<bool OUTF32>
__device__ __forceinline__ void gemm_core(
  unsigned short* As, unsigned short* Bs,      // [3][128*32] each
  const unsigned short* __restrict__ A, int lda,
  const unsigned short* __restrict__ BT,
  const float* __restrict__ bias,
  void* __restrict__ Cv, int ldc,
  int N, int K, int bx, int by)
{
  const int tid = threadIdx.x;
  const int wave = tid>>6, lane = tid&63, lq = lane&15, lg = lane>>4;
  const int tm = by*128, tn = bx*128;
  const int wm = (wave>>1)*64, wn = (wave&1)*64;
  f32x4 acc[4][4] = {};
  char* AsB = (char*)As; char* BsB = (char*)Bs;
  const int r4 = tid>>2;
  const int rowS0 = r4, rowS1 = 64 + r4;
  const int c0 = ((tid&3) ^ ((rowS0 ^ (rowS0>>2)) & 3))*8;
  const int c1 = ((tid&3) ^ ((rowS1 ^ (rowS1>>2)) & 3))*8;
  const unsigned short* Arow0 = A  + (size_t)(tm + rowS0)*lda + c0;
  const unsigned short* Arow1 = A  + (size_t)(tm + rowS1)*lda + c1;
  const unsigned short* Brow0 = BT + (size_t)(tn + rowS0)*K   + c0;
  const unsigned short* Brow1 = BT + (size_t)(tn + rowS1)*K   + c1;
  const int nt = K >> 5;

#define GSTAGE(t_) do { const int bq_ = ((t_)%3)*8192; const int kk_ = (t_)*32; \
    GLOAD16(Arow0 + kk_, AsB + bq_ +        tid*16);                            \
    GLOAD16(Arow1 + kk_, AsB + bq_ + 4096 + tid*16);                            \
    GLOAD16(Brow0 + kk_, BsB + bq_ +        tid*16);                            \
    GLOAD16(Brow1 + kk_, BsB + bq_ + 4096 + tid*16); } while(0)

  GSTAGE(0); GSTAGE(1);
  asm volatile("s_waitcnt vmcnt(4)" ::: "memory");
  __builtin_amdgcn_s_barrier();
  for (int t = 0; t < nt; t++){
    const int cur = t%3;
    if (t+2 < nt) GSTAGE(t+2);
    bf16x8 af[4], bfr[4];
    #pragma unroll
    for (int i=0;i<4;i++){
      int row = wm+16*i+lq;
      af[i]  = *(const bf16x8*)(AsB + cur*8192 + row*64 + ((lg ^ ((row ^ (row>>2))&3))<<4));
    }
    #pragma unroll
    for (int j=0;j<4;j++){
      int row = wn+16*j+lq;
      bfr[j] = *(const bf16x8*)(BsB + cur*8192 + row*64 + ((lg ^ ((row ^ (row>>2))&3))<<4));
    }
    #pragma unroll
    for (int i=0;i<4;i++)
      #pragma unroll
      for (int j=0;j<4;j++)
        acc[i][j] = __builtin_amdgcn_mfma_f32_16x16x32_bf16(af[i], bfr[j], acc[i][j], 0,0,0);
    if (t+2 < nt) asm volatile("s_waitcnt vmcnt(4)" ::: "memory");
    else          asm volatile("s_waitcnt vmcnt(0)" ::: "memory");
    __builtin_amdgcn_s_barrier();
  }
#undef GSTAGE

  #pragma unroll
  for (int i=0;i<4;i++){
    #pragma unroll
    for (int j=0;j<4;j++){
      int col = tn + wn + 16*j + lq;
      if (col < N){
        float bv = bias ? bias[col] : 0.f;
        #pragma unroll
        for (int r=0;r<4;r++){
          int row = tm + wm + 16*i + lg*4 + r;
          float v = acc[i][j][r] + bv;
          if (OUTF32) ((float*)Cv)[(size_t)row*ldc + col] = v;
          else ((unsigned short*)Cv)[(size_t)row*ldc + col] = f2bf(v);
        }
      }
    }
  }
}

// XCD-chunked bijective remap (requires nwg % 8 == 0 — all our grids comply)
__device__ __forceinline__ void xcd_remap(int& bx, int& by){
  int nwg = gridDim.x*gridDim.y;
  int lin = blockIdx.y*gridDim.x + blockIdx.x;
  int wg = (lin&7)*(nwg>>3) + (lin>>3);
  bx = wg % gridDim.x; by = wg / gridDim.x;
}

template<bool OUTF32>
__global__ __launch_bounds__(256) void gemm_bt(
  const unsigned short* __restrict__ A, int lda,
  const unsigned short* __restrict__ BT,
  const float* __restrict__ bias,
  void* __restrict__ Cv, int ldc, int N, int K)
{
  __shared__ unsigned short As[3*128*32];
  __shared__ unsigned short Bs[3*128*32];
  int bx, by; xcd_remap(bx, by);
  gemm_core<OUTF32>(As, Bs, A, lda, BT, bias, Cv, ldc, N, K, bx, by);
}

__global__ __launch_bounds__(256) void gemm_bt_dual(
  const unsigned short* __restrict__ A0, int lda0, const unsigned short* __restrict__ BT0,
  const float* __restrict__ b0, void* __restrict__ C0, int ldc0, int N0, int K0,
  const unsigned short* __restrict__ A1, int lda1, const unsigned short* __restrict__ BT1,
  const float* __restrict__ b1, void* __restrict__ C1, int ldc1, int N1, int K1,
  int split)
{
  __shared__ unsigned short As[3*128*32];
  __shared__ unsigned short Bs[3*128*32];
  int bx, by; xcd_remap(bx, by);
  if (bx < split)
    gemm_core<false>(As, Bs, A0, lda0, BT0, b0, C0, ldc0, N0, K0, bx, by);
  else
    gemm_core<false>(As, Bs, A1, lda1, BT1, b1, C1, ldc1, N1, K1, bx - split, by);
}

// ---------- fused: rmsnorm(cq), rmsnorm(ckv), rope_k ----------
__device__ __forceinline__ void rms_row(unsigned short* x, int D, float* red){
  int tid = threadIdx.x;
  float ss = 0.f;
  for (int i = tid; i < D; i += 256){ float v = bf2f(x[i]); ss += v*v; }
  #pragma unroll
  for (int o=32;o;o>>=1) ss += __shfl_xor(ss, o, 64);
  if ((tid&63)==0) red[tid>>6] = ss;
  __syncthreads();
  float tot = red[0]+red[1]+red[2]+red[3];
  float sc = rsqrtf(tot/(float)D + 1e-6f);
  for (int i = tid; i < D; i += 256) x[i] = f2bf(bf2f(x[i])*sc);
}

__global__ void norms_fused(unsigned short* __restrict__ cq,
                            unsigned short* __restrict__ ckv,
                            unsigned short* __restrict__ kr){
  __shared__ float red[4];
  int bid = blockIdx.x;
  if (bid < NTOK){
    rms_row(cq + (size_t)bid*QLR, QLR, red);
  } else if (bid < 2*NTOK){
    rms_row(ckv + (size_t)(bid-NTOK)*CKVD + DR, KVLR, red);
  } else {
    int idx = (bid - 2*NTOK)*256 + threadIdx.x;
    int j = idx & 31;
    int t = idx >> 5;
    int s = t & (SS-1);
    const unsigned short* src = ckv + (size_t)t*CKVD;
    float xr = bf2f(src[j]), xi = bf2f(src[j+32]);
    float freq = powf(10000.f, -(float)(2*j)/64.f);
    float ang = (float)s * freq;
    float c = cosf(ang), sn = sinf(ang);
    kr[(size_t)t*64 + j]      = f2bf(xr*c - xi*sn);
    kr[(size_t)t*64 + j + 32] = f2bf(xi*c + xr*sn);
  }
}

// ---------- fused: rope_q (in-place) + V transpose ----------
__global__ void ropeq_vt_fused(unsigned short* __restrict__ q,
                               const unsigned short* __restrict__ kv,
                               unsigned short* __restrict__ vT){
  int bid = blockIdx.x;
  if (bid < NTOK*NH*32/256){
    int idx = bid*256 + threadIdx.x;   // B*S*H*32
    int j = idx & 31;
    int h = (idx >> 5) & 15;
    int t = idx >> 9;            // token
    int s = t & (SS-1);
    unsigned short* base = q + (size_t)t*QD + h*(DN+DR) + DN;
    float xr = bf2f(base[j]), xi = bf2f(base[j+32]);
    float freq = powf(10000.f, -(float)(2*j)/64.f);
    float ang = (float)s * freq;
    float c = cosf(ang), sn = sinf(ang);
    base[j]    = f2bf(xr*c - xi*sn);
    base[j+32] = f2bf(xi*c + xr*sn);
  } else {
    __shared__ unsigned short t[32][33];
    int idx = bid - NTOK*NH*32/256;    // 8192 tiles: (s0i 64, d0i 4, bh 32)
    int s0 = (idx & 63)*32, d0 = ((idx>>6)&3)*32, bh = idx>>8;
    int b = bh>>4, h = bh&15;
    int tx = threadIdx.x & 31, ty = threadIdx.x >> 5;
    #pragma unroll
    for (int i = ty; i < 32; i += 8)
      t[i][tx] = kv[((size_t)(b*SS + s0+i))*KVD + h*(DN+DV) + DN + d0 + tx];
    __syncthreads();
    #pragma unroll
    for (int i = ty; i < 32; i += 8)
      vT[((size_t)(bh*DV + d0+i))*SS + s0 + tx] = t[tx][i];
  }
}

// ---------- causal flash attention (32x32x16 MFMA) — round-7 kernel ----------
// 512 blocks = 16 q-tiles(128 rows) x 32 bh; 4 waves x 32 q-rows each.
// XCD decode keeps a bh's blocks on one XCD; qt = 15-(lin>>5) big-first.
__global__ __launch_bounds__(256) void attn_kernel(
  const unsigned short* __restrict__ q,   // [NTOK][3072] rope-applied
  const unsigned short* __restrict__ kv,  // [NTOK][4096]
  const unsigned short* __restrict__ kr,  // [NTOK][64] roped
  const unsigned short* __restrict__ vT,  // [32][128][S]
  unsigned short* __restrict__ attn)      // [NTOK][2048]
{
  __shared__ unsigned short Ksn[2][32*128];  // 8 KB each
  __shared__ unsigned short Ksr[2][32*64];   // 4 KB each
  __shared__ unsigned short Vs [2][128*32];  // 8 KB each
  __shared__ unsigned short Ps [4*32*36];    // per-wave 32 rows x 72 B
  const int tid = threadIdx.x, wave = tid>>6, lane = tid&63;
  const int lo = lane&31, hi = lane>>5;
  const int lin = blockIdx.x;
  const int bh = (lin&7) + 8*((lin>>3)&3);
  const int qt = NQT2-1 - (lin>>5);
  const int b = bh>>4, h = bh&15;
  const float kmul = 1.44269504f * 0.07216878364f; // log2e / sqrt(192)

  const int rK = tid>>4, cK = (tid&15) ^ (rK&7);
  const int rR = tid>>3, cR = (tid&7) ^ (rR&7);
  const int rV = tid>>2, cV = (tid&3) ^ (rV&3);
  const unsigned short* pKn0 = kv + (size_t)(b*SS + rK)*KVD + h*(DN+DV) + cK*8;
  const unsigned short* pKn1 = pKn0 + (size_t)16*KVD;
  const unsigned short* pKr  = kr + (size_t)(b*SS + rR)*64 + cR*8;
  const unsigned short* pV0  = vT + ((size_t)bh*DV + rV)*SS + cV*8;
  const unsigned short* pV1  = pV0 + (size_t)64*SS;

#define STAGE_ATTN(bufi) do {                                                 \
    GLOAD16(pKn0, (char*)Ksn[bufi] +        wave*1024);                       \
    GLOAD16(pKn1, (char*)Ksn[bufi] + 4096 + wave*1024);                       \
    GLOAD16(pKr,  (char*)Ksr[bufi] +        wave*1024);                       \
    GLOAD16(pV0,  (char*)Vs[bufi]  +        wave*1024);                       \
    GLOAD16(pV1,  (char*)Vs[bufi]  + 4096 + wave*1024);                       \
    pKn0 += 32*KVD; pKn1 += 32*KVD; pKr += 32*64; pV0 += 32; pV1 += 32;       \
  } while(0)

  const int qw = qt*128 + wave*32;
  const int myq = qw + lo;
  bf16x8 qf[12];
  {
    const unsigned short* qrow = q + (size_t)(b*SS + myq)*QD + h*(DN+DR);
    #pragma unroll
    for (int c=0;c<12;c++) qf[c] = *(const bf16x8*)(qrow + c*16 + hi*8);
  }
  f32x16 oacc[4] = {};
  float m = -1e30f, lsum = 0.f;
  const int nkt = 4*qt + 4;

  STAGE_ATTN(0);
  asm volatile("s_waitcnt vmcnt(0)" ::: "memory");
  __builtin_amdgcn_s_barrier();
  int cur = 0;
  for (int kt = 0; kt < nkt; kt++){
    if (kt+1 < nkt) STAGE_ATTN(cur^1);
    // ---- QK^T: S^T[key=32][q=32], A = K-tile rows, B = Q regs ----
    f32x16 sacc = {};
    __builtin_amdgcn_s_setprio(1);
    #pragma unroll
    for (int ck=0;ck<8;ck++){
      bf16x8 kf = *(const bf16x8*)((char*)Ksn[cur] + lo*256 + ((((ck*2+hi)^(lo&7)))<<4));
      sacc = __builtin_amdgcn_mfma_f32_32x32x16_bf16(kf, qf[ck], sacc, 0,0,0);
    }
    #pragma unroll
    for (int ck=0;ck<4;ck++){
      bf16x8 kf = *(const bf16x8*)((char*)Ksr[cur] + lo*128 + ((((ck*2+hi)^(lo&7)))<<4));
      sacc = __builtin_amdgcn_mfma_f32_32x32x16_bf16(kf, qf[8+ck], sacc, 0,0,0);
    }
    __builtin_amdgcn_s_setprio(0);
    // ---- online softmax: key-row(r) = (r&3)+8*(r>>2)+4*hi, q-col = lo ----
    float s[16]; float pmax = -1e30f;
    if (kt*32 + 31 <= qw){
      #pragma unroll
      for (int r=0;r<16;r++){ float v = sacc[r]*kmul; s[r]=v; pmax=fmaxf(pmax,v); }
    } else {
      #pragma unroll
      for (int r=0;r<16;r++){
        int kpos = kt*32 + (r&3) + 8*(r>>2) + 4*hi;
        float v = (kpos <= myq) ? sacc[r]*kmul : -1e30f;
        s[r]=v; pmax=fmaxf(pmax,v);
      }
    }
    pmax = fmaxf(pmax, __shfl_xor(pmax, 32, 64));
    if (!__all(pmax <= m + 8.f)){   // defer-max
      float mnew = fmaxf(m, pmax);
      float alpha = __builtin_amdgcn_exp2f(m - mnew);
      m = mnew; lsum *= alpha;
      #pragma unroll
      for (int dt=0;dt<4;dt++)
        #pragma unroll
        for (int r=0;r<16;r++) oacc[dt][r] *= alpha;
    }
    float psum = 0.f;
    #pragma unroll
    for (int r=0;r<16;r++){ s[r] = __builtin_amdgcn_exp2f(s[r] - m); psum += s[r]; }
    psum += __shfl_xor(psum, 32, 64);
    lsum += psum;
    // ---- P -> per-wave padded LDS tile, then B-fragments ----
    unsigned short* Pw = Ps + wave*32*36;
    #pragma unroll
    for (int rg=0; rg<4; rg++){
      uint2 pk = { cvt_pk_bf16(s[rg*4+0], s[rg*4+1]),
                   cvt_pk_bf16(s[rg*4+2], s[rg*4+3]) };
      *(uint2*)((char*)Pw + lo*72 + rg*16 + hi*8) = pk;
    }
    bf16x8 pf[2];
    #pragma unroll
    for (int j=0;j<2;j++){
      uint2 a0 = *(const uint2*)((char*)Pw + lo*72 + (2*j+hi)*16);
      uint2 a1 = *(const uint2*)((char*)Pw + lo*72 + (2*j+hi)*16 + 8);
      u32x4 pk4 = { a0.x, a0.y, a1.x, a1.y };
      pf[j] = __builtin_bit_cast(bf16x8, pk4);
    }
    // ---- PV: O[d=32][q=32] per d-tile, A = V^T rows, B = pf ----
    __builtin_amdgcn_s_setprio(1);
    #pragma unroll
    for (int dt=0; dt<4; dt++){
      const int row = dt*32 + lo;
      #pragma unroll
      for (int j=0;j<2;j++){
        bf16x8 vf = *(const bf16x8*)((char*)Vs[cur] + row*64 + ((((j*2+hi)^(lo&3)))<<4));
        oacc[dt] = __builtin_amdgcn_mfma_f32_32x32x16_bf16(vf, pf[j], oacc[dt], 0,0,0);
      }
    }
    __builtin_amdgcn_s_setprio(0);
    asm volatile("s_waitcnt vmcnt(0)" ::: "memory");
    __builtin_amdgcn_s_barrier();
    cur ^= 1;
  }
  // ---- epilogue: O rows d = (r&3)+8*(r>>2)+4*hi+32*dt, col q = lo ----
  float inv = 1.f / lsum;
  unsigned short* orow = attn + (size_t)(b*SS + myq)*2048 + h*DV;
  #pragma unroll
  for (int dt=0; dt<4; dt++){
    #pragma unroll
    for (int rq=0; rq<4; rq++){
      int dbase = dt*32 + rq*8 + hi*4;
      uint2 o = { cvt_pk_bf16(oacc[dt][rq*4+0]*inv, oacc[dt][rq*4+1]*inv),
                  cvt_pk_bf16(oacc[dt][rq*4+2]*inv, oacc[dt][rq*4+3]*inv) };
      *(uint2*)(orow + dbase) = o;
    }
  }
#undef STAGE_ATTN
}

// ---------- launch ----------
extern "C" void kernel_launch(void* const* d_in, const int* in_sizes, int n_in,
                              void* d_out, int out_size, void* d_ws, size_t ws_size,
                              hipStream_t stream){
  const float* X    = (const float*)d_in[0];
  const float* Wqd  = (const float*)d_in[2];
  const float* bqd  = (const float*)d_in[3];
  const float* Wqu  = (const float*)d_in[4];
  const float* bqu  = (const float*)d_in[5];
  const float* Wkvd = (const float*)d_in[6];
  const float* bkvd = (const float*)d_in[7];
  const float* Wkvu = (const float*)d_in[8];
  const float* bkvu = (const float*)d_in[9];
  const float* Wo   = (const float*)d_in[10];
  const float* bo   = (const float*)d_in[11];
  float* out = (float*)d_out;

  char* ws = (char*)d_ws;
  // workspace layout (bytes); attn output overlays Xb (dead after G1G3)
  unsigned short* Xb    = (unsigned short*)(ws + 0);          // 16,777,216
  unsigned short* attnb = (unsigned short*)(ws + 0);
  char*           arena = ws + 16777216;                      // weight arena
  unsigned short* Wt1 = (unsigned short*)(arena);             // 1536x2048x2 = 6,291,456
  unsigned short* Wt3 = (unsigned short*)(arena + 6291456);   // 640x2048x2  = 2,621,440
  unsigned short* Wt2 = (unsigned short*)(arena);             // 3072x1536x2 = 9,437,184
  unsigned short* Wt4 = (unsigned short*)(arena + 9437184);   // 4096x512x2  = 4,194,304
  unsigned short* Wt5 = (unsigned short*)(arena);             // 2048x2048x2 = 8,388,608
  unsigned short* cq   = (unsigned short*)(ws + 31457280);    // 12,582,912
  unsigned short* qtmp = (unsigned short*)(ws + 44040192);    // 25,165,824
  unsigned short* ckv  = (unsigned short*)(ws + 69206016);    //  4,718,592
  unsigned short* kvt  = (unsigned short*)(ws + 73924608);    // 33,554,432
  unsigned short* kr   = (unsigned short*)(ws + 107479040);   //    524,288
  unsigned short* vT   = (unsigned short*)(ws + 108003328);   // 16,777,216  (end 124,780,544)

  // 1. X -> bf16
  cvt_f32_bf16<<<dim3(NTOK*HID/4/256), 256, 0, stream>>>(X, Xb, NTOK*HID/4);
  // 2. W transposes for down-projections, fused G1+G3
  wtrans<<<dim3(QLR/32, HID/32), 256, 0, stream>>>(Wqd, Wt1, HID, QLR);
  wtrans<<<dim3(640/32, HID/32), 256, 0, stream>>>(Wkvd, Wt3, HID, CKVD);
  gemm_bt_dual<<<dim3(QLR/128 + 640/128, NTOK/128), 256, 0, stream>>>(
      Xb, HID, Wt1, bqd, cq, QLR, QLR, HID,
      Xb, HID, Wt3, bkvd, ckv, CKVD, CKVD, HID, QLR/128);
  // 3. norms + k rope (fused)
  norms_fused<<<dim3(2*NTOK + NTOK*32/256), 256, 0, stream>>>(cq, ckv, kr);
  // 4. W transposes for up-projections, fused G2+G4
  wtrans<<<dim3(QD/32, QLR/32), 256, 0, stream>>>(Wqu, Wt2, QLR, QD);
  wtrans<<<dim3(KVD/32, KVLR/32), 256, 0, stream>>>(Wkvu, Wt4, KVLR, KVD);
  gemm_bt_dual<<<dim3(QD/128 + KVD/128, NTOK/128), 256, 0, stream>>>(
      cq, QLR, Wt2, bqu, qtmp, QD, QD, QLR,
      ckv + DR, CKVD, Wt4, bkvu, kvt, KVD, KVD, KVLR, QD/128);
  // 5. q rope + V^T (fused)
  ropeq_vt_fused<<<dim3(NTOK*NH*32/256 + 8192), 256, 0, stream>>>(qtmp, kvt, vT);
  // 6. attention (512 blocks, 32x32 MFMA, XCD-grouped, big-qt first)
  attn_kernel<<<dim3(NQT2 * BB*NH), 256, 0, stream>>>(qtmp, kvt, kr, vT, attnb);
  // 7. Wo^T ; GEMM5 -> out (f32)
  wtrans<<<dim3(HID/32, HID/32), 256, 0, stream>>>(Wo, Wt5, HID, HID);
  gemm_bt<true><<<dim3(HID/128, NTOK/128), 256, 0, stream>>>(attnb, HID, Wt5, bo, out, HID, HID, HID);
}

// Round 10
// 363.032 us; speedup vs baseline: 1.1121x; 1.0749x over previous
//
#include <hip/hip_runtime.h>

// ---------- constants ----------
#define HID 2048
#define NH 16
#define QLR 1536
#define KVLR 512
#define DN 128
#define DR 64
#define DV 128
#define BB 2
#define SS 2048
#define NTOK (BB*SS)   // 4096
#define QD 3072        // H*(DN+DR)
#define KVD 4096       // H*(DN+DV)
#define CKVD 576       // DR+KVLR
#define NQT2 (SS/128)  // 16 q-tiles of 128

typedef __bf16 bf16x8 __attribute__((ext_vector_type(8)));
typedef float f32x4 __attribute__((ext_vector_type(4)));
typedef float f32x16 __attribute__((ext_vector_type(16)));
typedef unsigned short us4v __attribute__((ext_vector_type(4)));
typedef unsigned int u32x4 __attribute__((ext_vector_type(4)));

__device__ __forceinline__ unsigned short f2bf(float f){
  unsigned u = __builtin_bit_cast(unsigned, f);
  return (unsigned short)((u + 0x7fffu + ((u>>16)&1u)) >> 16);
}
__device__ __forceinline__ float bf2f(unsigned short h){
  unsigned u = ((unsigned)h)<<16; return __builtin_bit_cast(float, u);
}
__device__ __forceinline__ unsigned cvt_pk_bf16(float a, float b){
  unsigned r;
  asm("v_cvt_pk_bf16_f32 %0, %1, %2" : "=v"(r) : "v"(a), "v"(b));
  return r;
}

#define GLOAD16(g, l) __builtin_amdgcn_global_load_lds( \
    (const __attribute__((address_space(1))) void*)(const void*)(g), \
    (__attribute__((address_space(3))) void*)(void*)(l), 16, 0, 0)

// ---------- fp32 -> bf16 convert (vectorized) ----------
__global__ void cvt_f32_bf16(const float* __restrict__ in, unsigned short* __restrict__ out, int n4){
  int i = blockIdx.x*256 + threadIdx.x;
  if (i < n4){
    float4 v = ((const float4*)in)[i];
    us4v o = { f2bf(v.x), f2bf(v.y), f2bf(v.z), f2bf(v.w) };
    ((us4v*)out)[i] = o;
  }
}

// ---------- weight transpose + convert: W[K][N] f32 -> WT[Npad][K] bf16 ----------
__global__ void wtrans(const float* __restrict__ W, unsigned short* __restrict__ WT,
                       int K, int N){
  __shared__ float t[32][33];
  int n0 = blockIdx.x*32, k0 = blockIdx.y*32;
  int tx = threadIdx.x & 31, ty = threadIdx.x >> 5;
  #pragma unroll
  for (int i = ty; i < 32; i += 8){
    int k = k0 + i, n = n0 + tx;
    t[i][tx] = (n < N) ? W[(size_t)k*N + n] : 0.f;
  }
  __syncthreads();
  #pragma unroll
  for (int i = ty; i < 32; i += 8){
    int n = n0 + i, k = k0 + tx;
    WT[(size_t)n*K + k] = f2bf(t[tx][i]);
  }
}

// ---------- bf16 GEMM core (round-7 proven): 128x128 tile, BK=64 ----------
// 4 waves, 16x16x32 MFMA, global_load_lds staging, 2-phase __syncthreads.
// LDS rows 128B -> XOR-chunk swizzle (chunk ^= row&7) on pre-swizzled global
// source + ds_read address (rule 21).
template<bool OUTF32>
__device__ __forceinline__ void gemm_core(
  unsigned short* As, unsigned short* Bs,
  const unsigned short* __restrict__ A, int lda,
  const unsigned short* __restrict__ BT,
  const float* __restrict__ bias,
  void* __restrict__ Cv, int ldc,
  int N, int K, int bx, int by)
{
  const int tid = threadIdx.x;
  const int wave = tid>>6, lane = tid&63, lq = lane&15, lg = lane>>4;
  const int tm = by*128, tn = bx*128;
  const int wm = (wave>>1)*64, wn = (wave&1)*64;
  f32x4 acc[4][4] = {};
  char* AsB = (char*)As; char* BsB = (char*)Bs;
  const int r8 = tid>>3;                 // row within 32-row group
  const int sc = ((tid&7) ^ (r8&7))*8;   // swizzled source col (shorts)
  for (int kt = 0; kt < K; kt += 64){
    __syncthreads();
    #pragma unroll
    for (int rd=0; rd<4; rd++){
      GLOAD16(A  + (size_t)(tm + rd*32 + r8)*lda + kt + sc, AsB + rd*4096 + wave*1024);
      GLOAD16(BT + (size_t)(tn + rd*32 + r8)*K   + kt + sc, BsB + rd*4096 + wave*1024);
    }
    asm volatile("s_waitcnt vmcnt(0)" ::: "memory");
    __syncthreads();
    #pragma unroll
    for (int h=0; h<2; h++){
      bf16x8 af[4], bfr[4];
      #pragma unroll
      for (int i=0;i<4;i++) af[i]  = *(const bf16x8*)(AsB + (wm+16*i+lq)*128 + ((((h*4+lg)^(lq&7)))<<4));
      #pragma unroll
      for (int j=0;j<4;j++) bfr[j] = *(const bf16x8*)(BsB + (wn+16*j+lq)*128 + ((((h*4+lg)^(lq&7)))<<4));
      #pragma unroll
      for (int i=0;i<4;i++)
        #pragma unroll
        for (int j=0;j<4;j++)
          acc[i][j] = __builtin_amdgcn_mfma_f32_16x16x32_bf16(af[i], bfr[j], acc[i][j], 0,0,0);
    }
  }
  #pragma unroll
  for (int i=0;i<4;i++){
    #pragma unroll
    for (int j=0;j<4;j++){
      int col = tn + wn + 16*j + lq;
      if (col < N){
        float bv = bias ? bias[col] : 0.f;
        #pragma unroll
        for (int r=0;r<4;r++){
          int row = tm + wm + 16*i + lg*4 + r;
          float v = acc[i][j][r] + bv;
          if (OUTF32) ((float*)Cv)[(size_t)row*ldc + col] = v;
          else ((unsigned short*)Cv)[(size_t)row*ldc + col] = f2bf(v);
        }
      }
    }
  }
}

// XCD-chunked bijective remap (requires nwg % 8 == 0 — all our grids comply)
__device__ __forceinline__ void xcd_remap(int& bx, int& by){
  int nwg = gridDim.x*gridDim.y;
  int lin = blockIdx.y*gridDim.x + blockIdx.x;
  int wg = (lin&7)*(nwg>>3) + (lin>>3);
  bx = wg % gridDim.x; by = wg / gridDim.x;
}

template<bool OUTF32>
__global__ __launch_bounds__(256) void gemm_bt(
  const unsigned short* __restrict__ A, int lda,
  const unsigned short* __restrict__ BT,
  const float* __restrict__ bias,
  void* __restrict__ Cv, int ldc, int N, int K)
{
  __shared__ unsigned short As[128*64];
  __shared__ unsigned short Bs[128*64];
  int bx, by; xcd_remap(bx, by);
  gemm_core<OUTF32>(As, Bs, A, lda, BT, bias, Cv, ldc, N, K, bx, by);
}

__global__ __launch_bounds__(256) void gemm_bt_dual(
  const unsigned short* __restrict__ A0, int lda0, const unsigned short* __restrict__ BT0,
  const float* __restrict__ b0, void* __restrict__ C0, int ldc0, int N0, int K0,
  const unsigned short* __restrict__ A1, int lda1, const unsigned short* __restrict__ BT1,
  const float* __restrict__ b1, void* __restrict__ C1, int ldc1, int N1, int K1,
  int split)
{
  __shared__ unsigned short As[128*64];
  __shared__ unsigned short Bs[128*64];
  int bx, by; xcd_remap(bx, by);
  if (bx < split)
    gemm_core<false>(As, Bs, A0, lda0, BT0, b0, C0, ldc0, N0, K0, bx, by);
  else
    gemm_core<false>(As, Bs, A1, lda1, BT1, b1, C1, ldc1, N1, K1, bx - split, by);
}

// ---------- fused: rmsnorm(cq), rmsnorm(ckv), rope_k ----------
__device__ __forceinline__ void rms_row(unsigned short* x, int D, float* red){
  int tid = threadIdx.x;
  float ss = 0.f;
  for (int i = tid; i < D; i += 256){ float v = bf2f(x[i]); ss += v*v; }
  #pragma unroll
  for (int o=32;o;o>>=1) ss += __shfl_xor(ss, o, 64);
  if ((tid&63)==0) red[tid>>6] = ss;
  __syncthreads();
  float tot = red[0]+red[1]+red[2]+red[3];
  float sc = rsqrtf(tot/(float)D + 1e-6f);
  for (int i = tid; i < D; i += 256) x[i] = f2bf(bf2f(x[i])*sc);
}

__global__ void norms_fused(unsigned short* __restrict__ cq,
                            unsigned short* __restrict__ ckv,
                            unsigned short* __restrict__ kr){
  __shared__ float red[4];
  int bid = blockIdx.x;
  if (bid < NTOK){
    rms_row(cq + (size_t)bid*QLR, QLR, red);
  } else if (bid < 2*NTOK){
    rms_row(ckv + (size_t)(bid-NTOK)*CKVD + DR, KVLR, red);
  } else {
    int idx = (bid - 2*NTOK)*256 + threadIdx.x;
    int j = idx & 31;
    int t = idx >> 5;
    int s = t & (SS-1);
    const unsigned short* src = ckv + (size_t)t*CKVD;
    float xr = bf2f(src[j]), xi = bf2f(src[j+32]);
    float freq = powf(10000.f, -(float)(2*j)/64.f);
    float ang = (float)s * freq;
    float c = cosf(ang), sn = sinf(ang);
    kr[(size_t)t*64 + j]      = f2bf(xr*c - xi*sn);
    kr[(size_t)t*64 + j + 32] = f2bf(xi*c + xr*sn);
  }
}

// ---------- fused: rope_q (in-place) + V transpose ----------
__global__ void ropeq_vt_fused(unsigned short* __restrict__ q,
                               const unsigned short* __restrict__ kv,
                               unsigned short* __restrict__ vT){
  int bid = blockIdx.x;
  if (bid < NTOK*NH*32/256){
    int idx = bid*256 + threadIdx.x;   // B*S*H*32
    int j = idx & 31;
    int h = (idx >> 5) & 15;
    int t = idx >> 9;            // token
    int s = t & (SS-1);
    unsigned short* base = q + (size_t)t*QD + h*(DN+DR) + DN;
    float xr = bf2f(base[j]), xi = bf2f(base[j+32]);
    float freq = powf(10000.f, -(float)(2*j)/64.f);
    float ang = (float)s * freq;
    float c = cosf(ang), sn = sinf(ang);
    base[j]    = f2bf(xr*c - xi*sn);
    base[j+32] = f2bf(xi*c + xr*sn);
  } else {
    __shared__ unsigned short t[32][33];
    int idx = bid - NTOK*NH*32/256;    // 8192 tiles: (s0i 64, d0i 4, bh 32)
    int s0 = (idx & 63)*32, d0 = ((idx>>6)&3)*32, bh = idx>>8;
    int b = bh>>4, h = bh&15;
    int tx = threadIdx.x & 31, ty = threadIdx.x >> 5;
    #pragma unroll
    for (int i = ty; i < 32; i += 8)
      t[i][tx] = kv[((size_t)(b*SS + s0+i))*KVD + h*(DN+DV) + DN + d0 + tx];
    __syncthreads();
    #pragma unroll
    for (int i = ty; i < 32; i += 8)
      vT[((size_t)(bh*DV + d0+i))*SS + s0 + tx] = t[tx][i];
  }
}

// ---------- causal flash attention (32x32x16 MFMA) ----------
// Round-7 structure; QK^T chain SPLIT into two independent accumulators
// (sacc0/sacc1, even/odd k-slices) — the 12-deep chained-MFMA dependency
// (~240 cyc at ~20cyc dep latency) was the dominant per-step serial term
// at 2 blocks/CU; 2 chains interleave in the MFMA pipe (m119: 2-8
// independent chains reach peak). Summed once per step (16 v_add).
__global__ __launch_bounds__(256) void attn_kernel(
  const unsigned short* __restrict__ q,   // [NTOK][3072] rope-applied
  const unsigned short* __restrict__ kv,  // [NTOK][4096]
  const unsigned short* __restrict__ kr,  // [NTOK][64] roped
  const unsigned short* __restrict__ vT,  // [32][128][S]
  unsigned short* __restrict__ attn)      // [NTOK][2048]
{
  __shared__ unsigned short Ksn[2][32*128];  // 8 KB each
  __shared__ unsigned short Ksr[2][32*64];   // 4 KB each
  __shared__ unsigned short Vs [2][128*32];  // 8 KB each
  __shared__ unsigned short Ps [4*32*36];    // per-wave 32 rows x 72 B
  const int tid = threadIdx.x, wave = tid>>6, lane = tid&63;
  const int lo = lane&31, hi = lane>>5;
  const int lin = blockIdx.x;
  const int bh = (lin&7) + 8*((lin>>3)&3);
  const int qt = NQT2-1 - (lin>>5);
  const int b = bh>>4, h = bh&15;
  const float kmul = 1.44269504f * 0.07216878364f; // log2e / sqrt(192)

  const int rK = tid>>4, cK = (tid&15) ^ (rK&7);
  const int rR = tid>>3, cR = (tid&7) ^ (rR&7);
  const int rV = tid>>2, cV = (tid&3) ^ (rV&3);
  const unsigned short* pKn0 = kv + (size_t)(b*SS + rK)*KVD + h*(DN+DV) + cK*8;
  const unsigned short* pKn1 = pKn0 + (size_t)16*KVD;
  const unsigned short* pKr  = kr + (size_t)(b*SS + rR)*64 + cR*8;
  const unsigned short* pV0  = vT + ((size_t)bh*DV + rV)*SS + cV*8;
  const unsigned short* pV1  = pV0 + (size_t)64*SS;

#define STAGE_ATTN(bufi) do {                                                 \
    GLOAD16(pKn0, (char*)Ksn[bufi] +        wave*1024);                       \
    GLOAD16(pKn1, (char*)Ksn[bufi] + 4096 + wave*1024);                       \
    GLOAD16(pKr,  (char*)Ksr[bufi] +        wave*1024);                       \
    GLOAD16(pV0,  (char*)Vs[bufi]  +        wave*1024);                       \
    GLOAD16(pV1,  (char*)Vs[bufi]  + 4096 + wave*1024);                       \
    pKn0 += 32*KVD; pKn1 += 32*KVD; pKr += 32*64; pV0 += 32; pV1 += 32;       \
  } while(0)

  const int qw = qt*128 + wave*32;
  const int myq = qw + lo;
  bf16x8 qf[12];
  {
    const unsigned short* qrow = q + (size_t)(b*SS + myq)*QD + h*(DN+DR);
    #pragma unroll
    for (int c=0;c<12;c++) qf[c] = *(const bf16x8*)(qrow + c*16 + hi*8);
  }
  f32x16 oacc[4] = {};
  float m = -1e30f, lsum = 0.f;
  const int nkt = 4*qt + 4;

  STAGE_ATTN(0);
  asm volatile("s_waitcnt vmcnt(0)" ::: "memory");
  __builtin_amdgcn_s_barrier();
  int cur = 0;
  for (int kt = 0; kt < nkt; kt++){
    if (kt+1 < nkt) STAGE_ATTN(cur^1);
    // ---- QK^T: S^T[key=32][q=32]; two independent MFMA chains ----
    f32x16 sacc0 = {}, sacc1 = {};
    __builtin_amdgcn_s_setprio(1);
    #pragma unroll
    for (int ck=0;ck<4;ck++){
      bf16x8 k0 = *(const bf16x8*)((char*)Ksn[cur] + lo*256 + (((((2*ck)*2+hi)^(lo&7)))<<4));
      bf16x8 k1 = *(const bf16x8*)((char*)Ksn[cur] + lo*256 + (((((2*ck+1)*2+hi)^(lo&7)))<<4));
      sacc0 = __builtin_amdgcn_mfma_f32_32x32x16_bf16(k0, qf[2*ck],   sacc0, 0,0,0);
      sacc1 = __builtin_amdgcn_mfma_f32_32x32x16_bf16(k1, qf[2*ck+1], sacc1, 0,0,0);
    }
    #pragma unroll
    for (int ck=0;ck<2;ck++){
      bf16x8 k0 = *(const bf16x8*)((char*)Ksr[cur] + lo*128 + (((((2*ck)*2+hi)^(lo&7)))<<4));
      bf16x8 k1 = *(const bf16x8*)((char*)Ksr[cur] + lo*128 + (((((2*ck+1)*2+hi)^(lo&7)))<<4));
      sacc0 = __builtin_amdgcn_mfma_f32_32x32x16_bf16(k0, qf[8+2*ck],   sacc0, 0,0,0);
      sacc1 = __builtin_amdgcn_mfma_f32_32x32x16_bf16(k1, qf[8+2*ck+1], sacc1, 0,0,0);
    }
    __builtin_amdgcn_s_setprio(0);
    f32x16 sacc = sacc0 + sacc1;
    // ---- online softmax: key-row(r) = (r&3)+8*(r>>2)+4*hi, q-col = lo ----
    float s[16]; float pmax = -1e30f;
    if (kt*32 + 31 <= qw){
      #pragma unroll
      for (int r=0;r<16;r++){ float v = sacc[r]*kmul; s[r]=v; pmax=fmaxf(pmax,v); }
    } else {
      #pragma unroll
      for (int r=0;r<16;r++){
        int kpos = kt*32 + (r&3) + 8*(r>>2) + 4*hi;
        float v = (kpos <= myq) ? sacc[r]*kmul : -1e30f;
        s[r]=v; pmax=fmaxf(pmax,v);
      }
    }
    pmax = fmaxf(pmax, __shfl_xor(pmax, 32, 64));
    if (!__all(pmax <= m + 8.f)){   // defer-max
      float mnew = fmaxf(m, pmax);
      float alpha = __builtin_amdgcn_exp2f(m - mnew);
      m = mnew; lsum *= alpha;
      #pragma unroll
      for (int dt=0;dt<4;dt++)
        #pragma unroll
        for (int r=0;r<16;r++) oacc[dt][r] *= alpha;
    }
    float psum = 0.f;
    #pragma unroll
    for (int r=0;r<16;r++){ s[r] = __builtin_amdgcn_exp2f(s[r] - m); psum += s[r]; }
    psum += __shfl_xor(psum, 32, 64);
    lsum += psum;
    // ---- P -> per-wave padded LDS tile, then B-fragments ----
    unsigned short* Pw = Ps + wave*32*36;
    #pragma unroll
    for (int rg=0; rg<4; rg++){
      uint2 pk = { cvt_pk_bf16(s[rg*4+0], s[rg*4+1]),
                   cvt_pk_bf16(s[rg*4+2], s[rg*4+3]) };
      *(uint2*)((char*)Pw + lo*72 + rg*16 + hi*8) = pk;
    }
    bf16x8 pf[2];
    #pragma unroll
    for (int j=0;j<2;j++){
      uint2 a0 = *(const uint2*)((char*)Pw + lo*72 + (2*j+hi)*16);
      uint2 a1 = *(const uint2*)((char*)Pw + lo*72 + (2*j+hi)*16 + 8);
      u32x4 pk4 = { a0.x, a0.y, a1.x, a1.y };
      pf[j] = __builtin_bit_cast(bf16x8, pk4);
    }
    // ---- PV: O[d=32][q=32] per d-tile, A = V^T rows, B = pf ----
    __builtin_amdgcn_s_setprio(1);
    #pragma unroll
    for (int dt=0; dt<4; dt++){
      const int row = dt*32 + lo;
      #pragma unroll
      for (int j=0;j<2;j++){
        bf16x8 vf = *(const bf16x8*)((char*)Vs[cur] + row*64 + ((((j*2+hi)^(lo&3)))<<4));
        oacc[dt] = __builtin_amdgcn_mfma_f32_32x32x16_bf16(vf, pf[j], oacc[dt], 0,0,0);
      }
    }
    __builtin_amdgcn_s_setprio(0);
    asm volatile("s_waitcnt vmcnt(0)" ::: "memory");
    __builtin_amdgcn_s_barrier();
    cur ^= 1;
  }
  // ---- epilogue: O rows d = (r&3)+8*(r>>2)+4*hi+32*dt, col q = lo ----
  float inv = 1.f / lsum;
  unsigned short* orow = attn + (size_t)(b*SS + myq)*2048 + h*DV;
  #pragma unroll
  for (int dt=0; dt<4; dt++){
    #pragma unroll
    for (int rq=0; rq<4; rq++){
      int dbase = dt*32 + rq*8 + hi*4;
      uint2 o = { cvt_pk_bf16(oacc[dt][rq*4+0]*inv, oacc[dt][rq*4+1]*inv),
                  cvt_pk_bf16(oacc[dt][rq*4+2]*inv, oacc[dt][rq*4+3]*inv) };
      *(uint2*)(orow + dbase) = o;
    }
  }
#undef STAGE_ATTN
}

// ---------- launch ----------
extern "C" void kernel_launch(void* const* d_in, const int* in_sizes, int n_in,
                              void* d_out, int out_size, void* d_ws, size_t ws_size,
                              hipStream_t stream){
  const float* X    = (const float*)d_in[0];
  const float* Wqd  = (const float*)d_in[2];
  const float* bqd  = (const float*)d_in[3];
  const float* Wqu  = (const float*)d_in[4];
  const float* bqu  = (const float*)d_in[5];
  const float* Wkvd = (const float*)d_in[6];
  const float* bkvd = (const float*)d_in[7];
  const float* Wkvu = (const float*)d_in[8];
  const float* bkvu = (const float*)d_in[9];
  const float* Wo   = (const float*)d_in[10];
  const float* bo   = (const float*)d_in[11];
  float* out = (float*)d_out;

  char* ws = (char*)d_ws;
  // workspace layout (bytes); attn output overlays Xb (dead after G1G3)
  unsigned short* Xb    = (unsigned short*)(ws + 0);          // 16,777,216
  unsigned short* attnb = (unsigned short*)(ws + 0);
  char*           arena = ws + 16777216;                      // weight arena
  unsigned short* Wt1 = (unsigned short*)(arena);             // 1536x2048x2 = 6,291,456
  unsigned short* Wt3 = (unsigned short*)(arena + 6291456);   // 640x2048x2  = 2,621,440
  unsigned short* Wt2 = (unsigned short*)(arena);             // 3072x1536x2 = 9,437,184
  unsigned short* Wt4 = (unsigned short*)(arena + 9437184);   // 4096x512x2  = 4,194,304
  unsigned short* Wt5 = (unsigned short*)(arena);             // 2048x2048x2 = 8,388,608
  unsigned short* cq   = (unsigned short*)(ws + 31457280);    // 12,582,912
  unsigned short* qtmp = (unsigned short*)(ws + 44040192);    // 25,165,824
  unsigned short* ckv  = (unsigned short*)(ws + 69206016);    //  4,718,592
  unsigned short* kvt  = (unsigned short*)(ws + 73924608);    // 33,554,432
  unsigned short* kr   = (unsigned short*)(ws + 107479040);   //    524,288
  unsigned short* vT   = (unsigned short*)(ws + 108003328);   // 16,777,216  (end 124,780,544)

  // 1. X -> bf16
  cvt_f32_bf16<<<dim3(NTOK*HID/4/256), 256, 0, stream>>>(X, Xb, NTOK*HID/4);
  // 2. W transposes for down-projections, fused G1+G3
  wtrans<<<dim3(QLR/32, HID/32), 256, 0, stream>>>(Wqd, Wt1, HID, QLR);
  wtrans<<<dim3(640/32, HID/32), 256, 0, stream>>>(Wkvd, Wt3, HID, CKVD);
  gemm_bt_dual<<<dim3(QLR/128 + 640/128, NTOK/128), 256, 0, stream>>>(
      Xb, HID, Wt1, bqd, cq, QLR, QLR, HID,
      Xb, HID, Wt3, bkvd, ckv, CKVD, CKVD, HID, QLR/128);
  // 3. norms + k rope (fused)
  norms_fused<<<dim3(2*NTOK + NTOK*32/256), 256, 0, stream>>>(cq, ckv, kr);
  // 4. W transposes for up-projections, fused G2+G4
  wtrans<<<dim3(QD/32, QLR/32), 256, 0, stream>>>(Wqu, Wt2, QLR, QD);
  wtrans<<<dim3(KVD/32, KVLR/32), 256, 0, stream>>>(Wkvu, Wt4, KVLR, KVD);
  gemm_bt_dual<<<dim3(QD/128 + KVD/128, NTOK/128), 256, 0, stream>>>(
      cq, QLR, Wt2, bqu, qtmp, QD, QD, QLR,
      ckv + DR, CKVD, Wt4, bkvu, kvt, KVD, KVD, KVLR, QD/128);
  // 5. q rope + V^T (fused)
  ropeq_vt_fused<<<dim3(NTOK*NH*32/256 + 8192), 256, 0, stream>>>(qtmp, kvt, vT);
  // 6. attention (512 blocks, 32x32 MFMA, XCD-grouped, big-qt first)
  attn_kernel<<<dim3(NQT2 * BB*NH), 256, 0, stream>>>(qtmp, kvt, kr, vT, attnb);
  // 7. Wo^T ; GEMM5 -> out (f32)
  wtrans<<<dim3(HID/32, HID/32), 256, 0, stream>>>(Wo, Wt5, HID, HID);
  gemm_bt<true><<<dim3(HID/128, NTOK/128), 256, 0, stream>>>(attnb, HID, Wt5, bo, out, HID, HID, HID);
}

// Round 11
// 357.265 us; speedup vs baseline: 1.1300x; 1.0161x over previous
//
#include <hip/hip_runtime.h>

// ---------- constants ----------
#define HID 2048
#define NH 16
#define QLR 1536
#define KVLR 512
#define DN 128
#define DR 64
#define DV 128
#define BB 2
#define SS 2048
#define NTOK (BB*SS)   // 4096
#define QD 3072        // H*(DN+DR)
#define KVD 4096       // H*(DN+DV)
#define CKVD 576       // DR+KVLR
#define NQT2 (SS/128)  // 16 q-tiles of 128

typedef __bf16 bf16x8 __attribute__((ext_vector_type(8)));
typedef float f32x4 __attribute__((ext_vector_type(4)));
typedef float f32x16 __attribute__((ext_vector_type(16)));
typedef unsigned short us4v __attribute__((ext_vector_type(4)));
typedef unsigned int u32x4 __attribute__((ext_vector_type(4)));

__device__ __forceinline__ unsigned short f2bf(float f){
  unsigned u = __builtin_bit_cast(unsigned, f);
  return (unsigned short)((u + 0x7fffu + ((u>>16)&1u)) >> 16);
}
__device__ __forceinline__ float bf2f(unsigned short h){
  unsigned u = ((unsigned)h)<<16; return __builtin_bit_cast(float, u);
}
__device__ __forceinline__ unsigned cvt_pk_bf16(float a, float b){
  unsigned r;
  asm("v_cvt_pk_bf16_f32 %0, %1, %2" : "=v"(r) : "v"(a), "v"(b));
  return r;
}

#define GLOAD16(g, l) __builtin_amdgcn_global_load_lds( \
    (const __attribute__((address_space(1))) void*)(const void*)(g), \
    (__attribute__((address_space(3))) void*)(void*)(l), 16, 0, 0)

// ---------- weight transpose tile: W[K][N] f32 -> WT[n][k] bf16 ----------
__device__ __forceinline__ void wtrans_tile(
  const float* __restrict__ W, unsigned short* __restrict__ WT,
  int K, int N, int n0, int k0, float (*t)[33])
{
  int tx = threadIdx.x & 31, ty = threadIdx.x >> 5;
  #pragma unroll
  for (int i = ty; i < 32; i += 8){
    int k = k0 + i, n = n0 + tx;
    t[i][tx] = (n < N) ? W[(size_t)k*N + n] : 0.f;
  }
  __syncthreads();
  #pragma unroll
  for (int i = ty; i < 32; i += 8){
    int n = n0 + i, k = k0 + tx;
    WT[(size_t)n*K + k] = f2bf(t[tx][i]);
  }
}

// ---------- fused prep (down): cvt X->bf16 + Wqd^T + Wkvd^T ----------
// 8192 cvt blocks + 48x64 Wqd tiles + 20x64 Wkvd tiles = 12544 blocks
__global__ void prep_down(const float* __restrict__ X, unsigned short* __restrict__ Xb,
                          const float* __restrict__ Wqd, unsigned short* __restrict__ Wt1,
                          const float* __restrict__ Wkvd, unsigned short* __restrict__ Wt3){
  __shared__ float t[32][33];
  int bid = blockIdx.x;
  if (bid < 8192){
    int i = bid*256 + threadIdx.x;
    float4 v = ((const float4*)X)[i];
    us4v o = { f2bf(v.x), f2bf(v.y), f2bf(v.z), f2bf(v.w) };
    ((us4v*)Xb)[i] = o;
  } else if (bid < 8192 + 3072){
    int g = bid - 8192;
    wtrans_tile(Wqd, Wt1, HID, QLR, (g % 48)*32, (g / 48)*32, t);
  } else {
    int g = bid - 11264;
    wtrans_tile(Wkvd, Wt3, HID, CKVD, (g % 20)*32, (g / 20)*32, t);
  }
}

// ---------- fused prep (up): Wqu^T + Wkvu^T ----------
// 96x48 + 128x16 = 6656 blocks
__global__ void prep_up(const float* __restrict__ Wqu, unsigned short* __restrict__ Wt2,
                        const float* __restrict__ Wkvu, unsigned short* __restrict__ Wt4){
  __shared__ float t[32][33];
  int bid = blockIdx.x;
  if (bid < 4608){
    wtrans_tile(Wqu, Wt2, QLR, QD, (bid % 96)*32, (bid / 96)*32, t);
  } else {
    int g = bid - 4608;
    wtrans_tile(Wkvu, Wt4, KVLR, KVD, (g % 128)*32, (g / 128)*32, t);
  }
}

// ---------- standalone wtrans (Wo) ----------
__global__ void wtrans(const float* __restrict__ W, unsigned short* __restrict__ WT,
                       int K, int N){
  __shared__ float t[32][33];
  wtrans_tile(W, WT, K, N, blockIdx.x*32, blockIdx.y*32, t);
}

// ---------- bf16 GEMM core (proven): 128x128 tile, BK=64 ----------
// 4 waves, 16x16x32 MFMA, global_load_lds staging, 2-phase __syncthreads.
// LDS rows 128B -> XOR-chunk swizzle (chunk ^= row&7) on pre-swizzled global
// source + ds_read address (rule 21).
template<bool OUTF32>
__device__ __forceinline__ void gemm_core(
  unsigned short* As, unsigned short* Bs,
  const unsigned short* __restrict__ A, int lda,
  const unsigned short* __restrict__ BT,
  const float* __restrict__ bias,
  void* __restrict__ Cv, int ldc,
  int N, int K, int bx, int by)
{
  const int tid = threadIdx.x;
  const int wave = tid>>6, lane = tid&63, lq = lane&15, lg = lane>>4;
  const int tm = by*128, tn = bx*128;
  const int wm = (wave>>1)*64, wn = (wave&1)*64;
  f32x4 acc[4][4] = {};
  char* AsB = (char*)As; char* BsB = (char*)Bs;
  const int r8 = tid>>3;                 // row within 32-row group
  const int sc = ((tid&7) ^ (r8&7))*8;   // swizzled source col (shorts)
  for (int kt = 0; kt < K; kt += 64){
    __syncthreads();
    #pragma unroll
    for (int rd=0; rd<4; rd++){
      GLOAD16(A  + (size_t)(tm + rd*32 + r8)*lda + kt + sc, AsB + rd*4096 + wave*1024);
      GLOAD16(BT + (size_t)(tn + rd*32 + r8)*K   + kt + sc, BsB + rd*4096 + wave*1024);
    }
    asm volatile("s_waitcnt vmcnt(0)" ::: "memory");
    __syncthreads();
    #pragma unroll
    for (int h=0; h<2; h++){
      bf16x8 af[4], bfr[4];
      #pragma unroll
      for (int i=0;i<4;i++) af[i]  = *(const bf16x8*)(AsB + (wm+16*i+lq)*128 + ((((h*4+lg)^(lq&7)))<<4));
      #pragma unroll
      for (int j=0;j<4;j++) bfr[j] = *(const bf16x8*)(BsB + (wn+16*j+lq)*128 + ((((h*4+lg)^(lq&7)))<<4));
      #pragma unroll
      for (int i=0;i<4;i++)
        #pragma unroll
        for (int j=0;j<4;j++)
          acc[i][j] = __builtin_amdgcn_mfma_f32_16x16x32_bf16(af[i], bfr[j], acc[i][j], 0,0,0);
    }
  }
  #pragma unroll
  for (int i=0;i<4;i++){
    #pragma unroll
    for (int j=0;j<4;j++){
      int col = tn + wn + 16*j + lq;
      if (col < N){
        float bv = bias ? bias[col] : 0.f;
        #pragma unroll
        for (int r=0;r<4;r++){
          int row = tm + wm + 16*i + lg*4 + r;
          float v = acc[i][j][r] + bv;
          if (OUTF32) ((float*)Cv)[(size_t)row*ldc + col] = v;
          else ((unsigned short*)Cv)[(size_t)row*ldc + col] = f2bf(v);
        }
      }
    }
  }
}

// XCD-chunked bijective remap (requires nwg % 8 == 0 — all our grids comply)
__device__ __forceinline__ void xcd_remap(int& bx, int& by){
  int nwg = gridDim.x*gridDim.y;
  int lin = blockIdx.y*gridDim.x + blockIdx.x;
  int wg = (lin&7)*(nwg>>3) + (lin>>3);
  bx = wg % gridDim.x; by = wg / gridDim.x;
}

template<bool OUTF32>
__global__ __launch_bounds__(256) void gemm_bt(
  const unsigned short* __restrict__ A, int lda,
  const unsigned short* __restrict__ BT,
  const float* __restrict__ bias,
  void* __restrict__ Cv, int ldc, int N, int K)
{
  __shared__ unsigned short As[128*64];
  __shared__ unsigned short Bs[128*64];
  int bx, by; xcd_remap(bx, by);
  gemm_core<OUTF32>(As, Bs, A, lda, BT, bias, Cv, ldc, N, K, bx, by);
}

__global__ __launch_bounds__(256) void gemm_bt_dual(
  const unsigned short* __restrict__ A0, int lda0, const unsigned short* __restrict__ BT0,
  const float* __restrict__ b0, void* __restrict__ C0, int ldc0, int N0, int K0,
  const unsigned short* __restrict__ A1, int lda1, const unsigned short* __restrict__ BT1,
  const float* __restrict__ b1, void* __restrict__ C1, int ldc1, int N1, int K1,
  int split)
{
  __shared__ unsigned short As[128*64];
  __shared__ unsigned short Bs[128*64];
  int bx, by; xcd_remap(bx, by);
  if (bx < split)
    gemm_core<false>(As, Bs, A0, lda0, BT0, b0, C0, ldc0, N0, K0, bx, by);
  else
    gemm_core<false>(As, Bs, A1, lda1, BT1, b1, C1, ldc1, N1, K1, bx - split, by);
}

// ---------- fused: rmsnorm(cq), rmsnorm(ckv), rope_k ----------
__device__ __forceinline__ void rms_row(unsigned short* x, int D, float* red){
  int tid = threadIdx.x;
  float ss = 0.f;
  for (int i = tid; i < D; i += 256){ float v = bf2f(x[i]); ss += v*v; }
  #pragma unroll
  for (int o=32;o;o>>=1) ss += __shfl_xor(ss, o, 64);
  if ((tid&63)==0) red[tid>>6] = ss;
  __syncthreads();
  float tot = red[0]+red[1]+red[2]+red[3];
  float sc = rsqrtf(tot/(float)D + 1e-6f);
  for (int i = tid; i < D; i += 256) x[i] = f2bf(bf2f(x[i])*sc);
}

__global__ void norms_fused(unsigned short* __restrict__ cq,
                            unsigned short* __restrict__ ckv,
                            unsigned short* __restrict__ kr){
  __shared__ float red[4];
  int bid = blockIdx.x;
  if (bid < NTOK){
    rms_row(cq + (size_t)bid*QLR, QLR, red);
  } else if (bid < 2*NTOK){
    rms_row(ckv + (size_t)(bid-NTOK)*CKVD + DR, KVLR, red);
  } else {
    int idx = (bid - 2*NTOK)*256 + threadIdx.x;
    int j = idx & 31;
    int t = idx >> 5;
    int s = t & (SS-1);
    const unsigned short* src = ckv + (size_t)t*CKVD;
    float xr = bf2f(src[j]), xi = bf2f(src[j+32]);
    float freq = powf(10000.f, -(float)(2*j)/64.f);
    float ang = (float)s * freq;
    float c = cosf(ang), sn = sinf(ang);
    kr[(size_t)t*64 + j]      = f2bf(xr*c - xi*sn);
    kr[(size_t)t*64 + j + 32] = f2bf(xi*c + xr*sn);
  }
}

// ---------- fused: rope_q (in-place) + V transpose ----------
__global__ void ropeq_vt_fused(unsigned short* __restrict__ q,
                               const unsigned short* __restrict__ kv,
                               unsigned short* __restrict__ vT){
  int bid = blockIdx.x;
  if (bid < NTOK*NH*32/256){
    int idx = bid*256 + threadIdx.x;   // B*S*H*32
    int j = idx & 31;
    int h = (idx >> 5) & 15;
    int t = idx >> 9;            // token
    int s = t & (SS-1);
    unsigned short* base = q + (size_t)t*QD + h*(DN+DR) + DN;
    float xr = bf2f(base[j]), xi = bf2f(base[j+32]);
    float freq = powf(10000.f, -(float)(2*j)/64.f);
    float ang = (float)s * freq;
    float c = cosf(ang), sn = sinf(ang);
    base[j]    = f2bf(xr*c - xi*sn);
    base[j+32] = f2bf(xi*c + xr*sn);
  } else {
    __shared__ unsigned short t[32][33];
    int idx = bid - NTOK*NH*32/256;    // 8192 tiles: (s0i 64, d0i 4, bh 32)
    int s0 = (idx & 63)*32, d0 = ((idx>>6)&3)*32, bh = idx>>8;
    int b = bh>>4, h = bh&15;
    int tx = threadIdx.x & 31, ty = threadIdx.x >> 5;
    #pragma unroll
    for (int i = ty; i < 32; i += 8)
      t[i][tx] = kv[((size_t)(b*SS + s0+i))*KVD + h*(DN+DV) + DN + d0 + tx];
    __syncthreads();
    #pragma unroll
    for (int i = ty; i < 32; i += 8)
      vT[((size_t)(bh*DV + d0+i))*SS + s0 + tx] = t[tx][i];
  }
}

// ---------- causal flash attention (32x32x16 MFMA) — round-7 proven ----------
// 512 blocks = 16 q-tiles(128 rows) x 32 bh; 4 waves x 32 q-rows each.
// XCD decode keeps a bh's blocks on one XCD; qt = 15-(lin>>5) big-first.
__global__ __launch_bounds__(256) void attn_kernel(
  const unsigned short* __restrict__ q,   // [NTOK][3072] rope-applied
  const unsigned short* __restrict__ kv,  // [NTOK][4096]
  const unsigned short* __restrict__ kr,  // [NTOK][64] roped
  const unsigned short* __restrict__ vT,  // [32][128][S]
  unsigned short* __restrict__ attn)      // [NTOK][2048]
{
  __shared__ unsigned short Ksn[2][32*128];  // 8 KB each
  __shared__ unsigned short Ksr[2][32*64];   // 4 KB each
  __shared__ unsigned short Vs [2][128*32];  // 8 KB each
  __shared__ unsigned short Ps [4*32*36];    // per-wave 32 rows x 72 B
  const int tid = threadIdx.x, wave = tid>>6, lane = tid&63;
  const int lo = lane&31, hi = lane>>5;
  const int lin = blockIdx.x;
  const int bh = (lin&7) + 8*((lin>>3)&3);
  const int qt = NQT2-1 - (lin>>5);
  const int b = bh>>4, h = bh&15;
  const float kmul = 1.44269504f * 0.07216878364f; // log2e / sqrt(192)

  const int rK = tid>>4, cK = (tid&15) ^ (rK&7);
  const int rR = tid>>3, cR = (tid&7) ^ (rR&7);
  const int rV = tid>>2, cV = (tid&3) ^ (rV&3);
  const unsigned short* pKn0 = kv + (size_t)(b*SS + rK)*KVD + h*(DN+DV) + cK*8;
  const unsigned short* pKn1 = pKn0 + (size_t)16*KVD;
  const unsigned short* pKr  = kr + (size_t)(b*SS + rR)*64 + cR*8;
  const unsigned short* pV0  = vT + ((size_t)bh*DV + rV)*SS + cV*8;
  const unsigned short* pV1  = pV0 + (size_t)64*SS;

#define STAGE_ATTN(bufi) do {                                                 \
    GLOAD16(pKn0, (char*)Ksn[bufi] +        wave*1024);                       \
    GLOAD16(pKn1, (char*)Ksn[bufi] + 4096 + wave*1024);                       \
    GLOAD16(pKr,  (char*)Ksr[bufi] +        wave*1024);                       \
    GLOAD16(pV0,  (char*)Vs[bufi]  +        wave*1024);                       \
    GLOAD16(pV1,  (char*)Vs[bufi]  + 4096 + wave*1024);                       \
    pKn0 += 32*KVD; pKn1 += 32*KVD; pKr += 32*64; pV0 += 32; pV1 += 32;       \
  } while(0)

  const int qw = qt*128 + wave*32;
  const int myq = qw + lo;
  bf16x8 qf[12];
  {
    const unsigned short* qrow = q + (size_t)(b*SS + myq)*QD + h*(DN+DR);
    #pragma unroll
    for (int c=0;c<12;c++) qf[c] = *(const bf16x8*)(qrow + c*16 + hi*8);
  }
  f32x16 oacc[4] = {};
  float m = -1e30f, lsum = 0.f;
  const int nkt = 4*qt + 4;

  STAGE_ATTN(0);
  asm volatile("s_waitcnt vmcnt(0)" ::: "memory");
  __builtin_amdgcn_s_barrier();
  int cur = 0;
  for (int kt = 0; kt < nkt; kt++){
    if (kt+1 < nkt) STAGE_ATTN(cur^1);
    // ---- QK^T: S^T[key=32][q=32], A = K-tile rows, B = Q regs ----
    f32x16 sacc = {};
    __builtin_amdgcn_s_setprio(1);
    #pragma unroll
    for (int ck=0;ck<8;ck++){
      bf16x8 kf = *(const bf16x8*)((char*)Ksn[cur] + lo*256 + ((((ck*2+hi)^(lo&7)))<<4));
      sacc = __builtin_amdgcn_mfma_f32_32x32x16_bf16(kf, qf[ck], sacc, 0,0,0);
    }
    #pragma unroll
    for (int ck=0;ck<4;ck++){
      bf16x8 kf = *(const bf16x8*)((char*)Ksr[cur] + lo*128 + ((((ck*2+hi)^(lo&7)))<<4));
      sacc = __builtin_amdgcn_mfma_f32_32x32x16_bf16(kf, qf[8+ck], sacc, 0,0,0);
    }
    __builtin_amdgcn_s_setprio(0);
    // ---- online softmax: key-row(r) = (r&3)+8*(r>>2)+4*hi, q-col = lo ----
    float s[16]; float pmax = -1e30f;
    if (kt*32 + 31 <= qw){
      #pragma unroll
      for (int r=0;r<16;r++){ float v = sacc[r]*kmul; s[r]=v; pmax=fmaxf(pmax,v); }
    } else {
      #pragma unroll
      for (int r=0;r<16;r++){
        int kpos = kt*32 + (r&3) + 8*(r>>2) + 4*hi;
        float v = (kpos <= myq) ? sacc[r]*kmul : -1e30f;
        s[r]=v; pmax=fmaxf(pmax,v);
      }
    }
    pmax = fmaxf(pmax, __shfl_xor(pmax, 32, 64));
    if (!__all(pmax <= m + 8.f)){   // defer-max
      float mnew = fmaxf(m, pmax);
      float alpha = __builtin_amdgcn_exp2f(m - mnew);
      m = mnew; lsum *= alpha;
      #pragma unroll
      for (int dt=0;dt<4;dt++)
        #pragma unroll
        for (int r=0;r<16;r++) oacc[dt][r] *= alpha;
    }
    float psum = 0.f;
    #pragma unroll
    for (int r=0;r<16;r++){ s[r] = __builtin_amdgcn_exp2f(s[r] - m); psum += s[r]; }
    psum += __shfl_xor(psum, 32, 64);
    lsum += psum;
    // ---- P -> per-wave padded LDS tile, then B-fragments ----
    unsigned short* Pw = Ps + wave*32*36;
    #pragma unroll
    for (int rg=0; rg<4; rg++){
      uint2 pk = { cvt_pk_bf16(s[rg*4+0], s[rg*4+1]),
                   cvt_pk_bf16(s[rg*4+2], s[rg*4+3]) };
      *(uint2*)((char*)Pw + lo*72 + rg*16 + hi*8) = pk;
    }
    bf16x8 pf[2];
    #pragma unroll
    for (int j=0;j<2;j++){
      uint2 a0 = *(const uint2*)((char*)Pw + lo*72 + (2*j+hi)*16);
      uint2 a1 = *(const uint2*)((char*)Pw + lo*72 + (2*j+hi)*16 + 8);
      u32x4 pk4 = { a0.x, a0.y, a1.x, a1.y };
      pf[j] = __builtin_bit_cast(bf16x8, pk4);
    }
    // ---- PV: O[d=32][q=32] per d-tile, A = V^T rows, B = pf ----
    __builtin_amdgcn_s_setprio(1);
    #pragma unroll
    for (int dt=0; dt<4; dt++){
      const int row = dt*32 + lo;
      #pragma unroll
      for (int j=0;j<2;j++){
        bf16x8 vf = *(const bf16x8*)((char*)Vs[cur] + row*64 + ((((j*2+hi)^(lo&3)))<<4));
        oacc[dt] = __builtin_amdgcn_mfma_f32_32x32x16_bf16(vf, pf[j], oacc[dt], 0,0,0);
      }
    }
    __builtin_amdgcn_s_setprio(0);
    asm volatile("s_waitcnt vmcnt(0)" ::: "memory");
    __builtin_amdgcn_s_barrier();
    cur ^= 1;
  }
  // ---- epilogue: O rows d = (r&3)+8*(r>>2)+4*hi+32*dt, col q = lo ----
  float inv = 1.f / lsum;
  unsigned short* orow = attn + (size_t)(b*SS + myq)*2048 + h*DV;
  #pragma unroll
  for (int dt=0; dt<4; dt++){
    #pragma unroll
    for (int rq=0; rq<4; rq++){
      int dbase = dt*32 + rq*8 + hi*4;
      uint2 o = { cvt_pk_bf16(oacc[dt][rq*4+0]*inv, oacc[dt][rq*4+1]*inv),
                  cvt_pk_bf16(oacc[dt][rq*4+2]*inv, oacc[dt][rq*4+3]*inv) };
      *(uint2*)(orow + dbase) = o;
    }
  }
#undef STAGE_ATTN
}

// ---------- launch ----------
extern "C" void kernel_launch(void* const* d_in, const int* in_sizes, int n_in,
                              void* d_out, int out_size, void* d_ws, size_t ws_size,
                              hipStream_t stream){
  const float* X    = (const float*)d_in[0];
  const float* Wqd  = (const float*)d_in[2];
  const float* bqd  = (const float*)d_in[3];
  const float* Wqu  = (const float*)d_in[4];
  const float* bqu  = (const float*)d_in[5];
  const float* Wkvd = (const float*)d_in[6];
  const float* bkvd = (const float*)d_in[7];
  const float* Wkvu = (const float*)d_in[8];
  const float* bkvu = (const float*)d_in[9];
  const float* Wo   = (const float*)d_in[10];
  const float* bo   = (const float*)d_in[11];
  float* out = (float*)d_out;

  char* ws = (char*)d_ws;
  // workspace layout (bytes); attn output overlays Xb (dead after G1G3)
  unsigned short* Xb    = (unsigned short*)(ws + 0);          // 16,777,216
  unsigned short* attnb = (unsigned short*)(ws + 0);
  char*           arena = ws + 16777216;                      // weight arena
  unsigned short* Wt1 = (unsigned short*)(arena);             // 1536x2048x2 = 6,291,456
  unsigned short* Wt3 = (unsigned short*)(arena + 6291456);   // 640x2048x2  = 2,621,440
  unsigned short* Wt2 = (unsigned short*)(arena);             // 3072x1536x2 = 9,437,184
  unsigned short* Wt4 = (unsigned short*)(arena + 9437184);   // 4096x512x2  = 4,194,304
  unsigned short* Wt5 = (unsigned short*)(arena);             // 2048x2048x2 = 8,388,608
  unsigned short* cq   = (unsigned short*)(ws + 31457280);    // 12,582,912
  unsigned short* qtmp = (unsigned short*)(ws + 44040192);    // 25,165,824
  unsigned short* ckv  = (unsigned short*)(ws + 69206016);    //  4,718,592
  unsigned short* kvt  = (unsigned short*)(ws + 73924608);    // 33,554,432
  unsigned short* kr   = (unsigned short*)(ws + 107479040);   //    524,288
  unsigned short* vT   = (unsigned short*)(ws + 108003328);   // 16,777,216  (end 124,780,544)

  // 1. fused: X->bf16 + Wqd^T + Wkvd^T (independent, one dispatch)
  prep_down<<<dim3(12544), 256, 0, stream>>>(X, Xb, Wqd, Wt1, Wkvd, Wt3);
  // 2. fused G1+G3
  gemm_bt_dual<<<dim3(QLR/128 + 640/128, NTOK/128), 256, 0, stream>>>(
      Xb, HID, Wt1, bqd, cq, QLR, QLR, HID,
      Xb, HID, Wt3, bkvd, ckv, CKVD, CKVD, HID, QLR/128);
  // 3. norms + k rope (fused)
  norms_fused<<<dim3(2*NTOK + NTOK*32/256), 256, 0, stream>>>(cq, ckv, kr);
  // 4. fused: Wqu^T + Wkvu^T ; fused G2+G4
  prep_up<<<dim3(6656), 256, 0, stream>>>(Wqu, Wt2, Wkvu, Wt4);
  gemm_bt_dual<<<dim3(QD/128 + KVD/128, NTOK/128), 256, 0, stream>>>(
      cq, QLR, Wt2, bqu, qtmp, QD, QD, QLR,
      ckv + DR, CKVD, Wt4, bkvu, kvt, KVD, KVD, KVLR, QD/128);
  // 5. q rope + V^T (fused)
  ropeq_vt_fused<<<dim3(NTOK*NH*32/256 + 8192), 256, 0, stream>>>(qtmp, kvt, vT);
  // 6. attention (512 blocks, 32x32 MFMA, XCD-grouped, big-qt first)
  attn_kernel<<<dim3(NQT2 * BB*NH), 256, 0, stream>>>(qtmp, kvt, kr, vT, attnb);
  // 7. Wo^T ; GEMM5 -> out (f32)
  wtrans<<<dim3(HID/32, HID/32), 256, 0, stream>>>(Wo, Wt5, HID, HID);
  gemm_bt<true><<<dim3(HID/128, NTOK/128), 256, 0, stream>>>(attnb, HID, Wt5, bo, out, HID, HID, HID);
}

// Round 12
// 345.530 us; speedup vs baseline: 1.1684x; 1.0340x over previous
//
#include <hip/hip_runtime.h>

// ---------- constants ----------
#define HID 2048
#define NH 16
#define QLR 1536
#define KVLR 512
#define DN 128
#define DR 64
#define DV 128
#define BB 2
#define SS 2048
#define NTOK (BB*SS)   // 4096
#define QD 3072        // H*(DN+DR)
#define KVD 4096       // H*(DN+DV)
#define CKVD 576       // DR+KVLR
#define NQT2 (SS/128)  // 16 q-tiles of 128

typedef __bf16 bf16x8 __attribute__((ext_vector_type(8)));
typedef float f32x4 __attribute__((ext_vector_type(4)));
typedef float f32x16 __attribute__((ext_vector_type(16)));
typedef unsigned short us4v __attribute__((ext_vector_type(4)));
typedef unsigned int u32x4 __attribute__((ext_vector_type(4)));

__device__ __forceinline__ unsigned short f2bf(float f){
  unsigned u = __builtin_bit_cast(unsigned, f);
  return (unsigned short)((u + 0x7fffu + ((u>>16)&1u)) >> 16);
}
__device__ __forceinline__ float bf2f(unsigned short h){
  unsigned u = ((unsigned)h)<<16; return __builtin_bit_cast(float, u);
}
__device__ __forceinline__ unsigned cvt_pk_bf16(float a, float b){
  unsigned r;
  asm("v_cvt_pk_bf16_f32 %0, %1, %2" : "=v"(r) : "v"(a), "v"(b));
  return r;
}

#define GLOAD16(g, l) __builtin_amdgcn_global_load_lds( \
    (const __attribute__((address_space(1))) void*)(const void*)(g), \
    (__attribute__((address_space(3))) void*)(void*)(l), 16, 0, 0)

// ---------- weight transpose tile: W[K][N] f32 -> WT[n][k] bf16 ----------
__device__ __forceinline__ void wtrans_tile(
  const float* __restrict__ W, unsigned short* __restrict__ WT,
  int K, int N, int n0, int k0, float (*t)[33])
{
  int tx = threadIdx.x & 31, ty = threadIdx.x >> 5;
  #pragma unroll
  for (int i = ty; i < 32; i += 8){
    int k = k0 + i, n = n0 + tx;
    t[i][tx] = (n < N) ? W[(size_t)k*N + n] : 0.f;
  }
  __syncthreads();
  #pragma unroll
  for (int i = ty; i < 32; i += 8){
    int n = n0 + i, k = k0 + tx;
    WT[(size_t)n*K + k] = f2bf(t[tx][i]);
  }
}

// ---------- fused prep (down): cvt X->bf16 + Wqd^T + Wkvd^T ----------
// 8192 cvt blocks + 48x64 Wqd tiles + 20x64 Wkvd tiles = 12544 blocks
__global__ void prep_down(const float* __restrict__ X, unsigned short* __restrict__ Xb,
                          const float* __restrict__ Wqd, unsigned short* __restrict__ Wt1,
                          const float* __restrict__ Wkvd, unsigned short* __restrict__ Wt3){
  __shared__ float t[32][33];
  int bid = blockIdx.x;
  if (bid < 8192){
    int i = bid*256 + threadIdx.x;
    float4 v = ((const float4*)X)[i];
    us4v o = { f2bf(v.x), f2bf(v.y), f2bf(v.z), f2bf(v.w) };
    ((us4v*)Xb)[i] = o;
  } else if (bid < 8192 + 3072){
    int g = bid - 8192;
    wtrans_tile(Wqd, Wt1, HID, QLR, (g % 48)*32, (g / 48)*32, t);
  } else {
    int g = bid - 11264;
    wtrans_tile(Wkvd, Wt3, HID, CKVD, (g % 20)*32, (g / 20)*32, t);
  }
}

// ---------- fused prep (up): Wqu^T + Wkvu^T ----------
// 96x48 + 128x16 = 6656 blocks
__global__ void prep_up(const float* __restrict__ Wqu, unsigned short* __restrict__ Wt2,
                        const float* __restrict__ Wkvu, unsigned short* __restrict__ Wt4){
  __shared__ float t[32][33];
  int bid = blockIdx.x;
  if (bid < 4608){
    wtrans_tile(Wqu, Wt2, QLR, QD, (bid % 96)*32, (bid / 96)*32, t);
  } else {
    int g = bid - 4608;
    wtrans_tile(Wkvu, Wt4, KVLR, KVD, (g % 128)*32, (g / 128)*32, t);
  }
}

// ---------- bf16 GEMM core (proven): 128x128 tile, BK=64 ----------
// 4 waves, 16x16x32 MFMA, global_load_lds staging, 2-phase __syncthreads.
// LDS rows 128B -> XOR-chunk swizzle (chunk ^= row&7) on pre-swizzled global
// source + ds_read address (rule 21).
template<bool OUTF32>
__device__ __forceinline__ void gemm_core(
  unsigned short* As, unsigned short* Bs,
  const unsigned short* __restrict__ A, int lda,
  const unsigned short* __restrict__ BT,
  const float* __restrict__ bias,
  void* __restrict__ Cv, int ldc,
  int N, int K, int bx, int by)
{
  const int tid = threadIdx.x;
  const int wave = tid>>6, lane = tid&63, lq = lane&15, lg = lane>>4;
  const int tm = by*128, tn = bx*128;
  const int wm = (wave>>1)*64, wn = (wave&1)*64;
  f32x4 acc[4][4] = {};
  char* AsB = (char*)As; char* BsB = (char*)Bs;
  const int r8 = tid>>3;                 // row within 32-row group
  const int sc = ((tid&7) ^ (r8&7))*8;   // swizzled source col (shorts)
  for (int kt = 0; kt < K; kt += 64){
    __syncthreads();
    #pragma unroll
    for (int rd=0; rd<4; rd++){
      GLOAD16(A  + (size_t)(tm + rd*32 + r8)*lda + kt + sc, AsB + rd*4096 + wave*1024);
      GLOAD16(BT + (size_t)(tn + rd*32 + r8)*K   + kt + sc, BsB + rd*4096 + wave*1024);
    }
    asm volatile("s_waitcnt vmcnt(0)" ::: "memory");
    __syncthreads();
    #pragma unroll
    for (int h=0; h<2; h++){
      bf16x8 af[4], bfr[4];
      #pragma unroll
      for (int i=0;i<4;i++) af[i]  = *(const bf16x8*)(AsB + (wm+16*i+lq)*128 + ((((h*4+lg)^(lq&7)))<<4));
      #pragma unroll
      for (int j=0;j<4;j++) bfr[j] = *(const bf16x8*)(BsB + (wn+16*j+lq)*128 + ((((h*4+lg)^(lq&7)))<<4));
      #pragma unroll
      for (int i=0;i<4;i++)
        #pragma unroll
        for (int j=0;j<4;j++)
          acc[i][j] = __builtin_amdgcn_mfma_f32_16x16x32_bf16(af[i], bfr[j], acc[i][j], 0,0,0);
    }
  }
  #pragma unroll
  for (int i=0;i<4;i++){
    #pragma unroll
    for (int j=0;j<4;j++){
      int col = tn + wn + 16*j + lq;
      if (col < N){
        float bv = bias ? bias[col] : 0.f;
        #pragma unroll
        for (int r=0;r<4;r++){
          int row = tm + wm + 16*i + lg*4 + r;
          float v = acc[i][j][r] + bv;
          if (OUTF32) ((float*)Cv)[(size_t)row*ldc + col] = v;
          else ((unsigned short*)Cv)[(size_t)row*ldc + col] = f2bf(v);
        }
      }
    }
  }
}

// XCD-chunked bijective remap (requires nwg % 8 == 0 — all our grids comply)
__device__ __forceinline__ void xcd_remap(int& bx, int& by){
  int nwg = gridDim.x*gridDim.y;
  int lin = blockIdx.y*gridDim.x + blockIdx.x;
  int wg = (lin&7)*(nwg>>3) + (lin>>3);
  bx = wg % gridDim.x; by = wg / gridDim.x;
}

template<bool OUTF32>
__global__ __launch_bounds__(256) void gemm_bt(
  const unsigned short* __restrict__ A, int lda,
  const unsigned short* __restrict__ BT,
  const float* __restrict__ bias,
  void* __restrict__ Cv, int ldc, int N, int K)
{
  __shared__ unsigned short As[128*64];
  __shared__ unsigned short Bs[128*64];
  int bx, by; xcd_remap(bx, by);
  gemm_core<OUTF32>(As, Bs, A, lda, BT, bias, Cv, ldc, N, K, bx, by);
}

__global__ __launch_bounds__(256) void gemm_bt_dual(
  const unsigned short* __restrict__ A0, int lda0, const unsigned short* __restrict__ BT0,
  const float* __restrict__ b0, void* __restrict__ C0, int ldc0, int N0, int K0,
  const unsigned short* __restrict__ A1, int lda1, const unsigned short* __restrict__ BT1,
  const float* __restrict__ b1, void* __restrict__ C1, int ldc1, int N1, int K1,
  int split)
{
  __shared__ unsigned short As[128*64];
  __shared__ unsigned short Bs[128*64];
  int bx, by; xcd_remap(bx, by);
  if (bx < split)
    gemm_core<false>(As, Bs, A0, lda0, BT0, b0, C0, ldc0, N0, K0, bx, by);
  else
    gemm_core<false>(As, Bs, A1, lda1, BT1, b1, C1, ldc1, N1, K1, bx - split, by);
}

// ---------- fused: rmsnorm(cq), rmsnorm(ckv), rope_k ----------
__device__ __forceinline__ void rms_row(unsigned short* x, int D, float* red){
  int tid = threadIdx.x;
  float ss = 0.f;
  for (int i = tid; i < D; i += 256){ float v = bf2f(x[i]); ss += v*v; }
  #pragma unroll
  for (int o=32;o;o>>=1) ss += __shfl_xor(ss, o, 64);
  if ((tid&63)==0) red[tid>>6] = ss;
  __syncthreads();
  float tot = red[0]+red[1]+red[2]+red[3];
  float sc = rsqrtf(tot/(float)D + 1e-6f);
  for (int i = tid; i < D; i += 256) x[i] = f2bf(bf2f(x[i])*sc);
}

__global__ void norms_fused(unsigned short* __restrict__ cq,
                            unsigned short* __restrict__ ckv,
                            unsigned short* __restrict__ kr){
  __shared__ float red[4];
  int bid = blockIdx.x;
  if (bid < NTOK){
    rms_row(cq + (size_t)bid*QLR, QLR, red);
  } else if (bid < 2*NTOK){
    rms_row(ckv + (size_t)(bid-NTOK)*CKVD + DR, KVLR, red);
  } else {
    int idx = (bid - 2*NTOK)*256 + threadIdx.x;
    int j = idx & 31;
    int t = idx >> 5;
    int s = t & (SS-1);
    const unsigned short* src = ckv + (size_t)t*CKVD;
    float xr = bf2f(src[j]), xi = bf2f(src[j+32]);
    float freq = powf(10000.f, -(float)(2*j)/64.f);
    float ang = (float)s * freq;
    float c = cosf(ang), sn = sinf(ang);
    kr[(size_t)t*64 + j]      = f2bf(xr*c - xi*sn);
    kr[(size_t)t*64 + j + 32] = f2bf(xi*c + xr*sn);
  }
}

// ---------- fused: rope_q (in-place) + V transpose + Wo^T ----------
// Runs after G2G4: weight arena (Wt2/Wt4) is dead -> Wt5 written here,
// concurrently with rope_q and V^T (saves a dispatch + tail).
__global__ void ropeq_vt_wo_fused(unsigned short* __restrict__ q,
                                  const unsigned short* __restrict__ kv,
                                  unsigned short* __restrict__ vT,
                                  const float* __restrict__ Wo,
                                  unsigned short* __restrict__ Wt5){
  __shared__ float tf[32][33];
  int bid = blockIdx.x;
  if (bid < 8192){
    int idx = bid*256 + threadIdx.x;   // B*S*H*32
    int j = idx & 31;
    int h = (idx >> 5) & 15;
    int t = idx >> 9;            // token
    int s = t & (SS-1);
    unsigned short* base = q + (size_t)t*QD + h*(DN+DR) + DN;
    float xr = bf2f(base[j]), xi = bf2f(base[j+32]);
    float freq = powf(10000.f, -(float)(2*j)/64.f);
    float ang = (float)s * freq;
    float c = cosf(ang), sn = sinf(ang);
    base[j]    = f2bf(xr*c - xi*sn);
    base[j+32] = f2bf(xi*c + xr*sn);
  } else if (bid < 16384){
    unsigned short (*t)[33] = (unsigned short(*)[33])tf;
    int idx = bid - 8192;              // 8192 tiles: (s0i 64, d0i 4, bh 32)
    int s0 = (idx & 63)*32, d0 = ((idx>>6)&3)*32, bh = idx>>8;
    int b = bh>>4, h = bh&15;
    int tx = threadIdx.x & 31, ty = threadIdx.x >> 5;
    #pragma unroll
    for (int i = ty; i < 32; i += 8)
      t[i][tx] = kv[((size_t)(b*SS + s0+i))*KVD + h*(DN+DV) + DN + d0 + tx];
    __syncthreads();
    #pragma unroll
    for (int i = ty; i < 32; i += 8)
      vT[((size_t)(bh*DV + d0+i))*SS + s0 + tx] = t[tx][i];
  } else {
    int g = bid - 16384;               // 64x64 tiles of Wo (2048x2048)
    wtrans_tile(Wo, Wt5, HID, HID, (g & 63)*32, (g >> 6)*32, tf);
  }
}

// ---------- causal flash attention (32x32x16 MFMA) ----------
// Round-7 structure, setprio REMOVED: with 2 barrier-synced 4-wave blocks
// per CU, the intended latency-hiding is block A's MFMA covering block B's
// softmax VALU; prio-1 MFMA deprioritizes the partner's VALU issue (m190:
// setprio hurts lockstep multi-wave kernels; m191's +7% was 1-wave blocks).
__global__ __launch_bounds__(256) void attn_kernel(
  const unsigned short* __restrict__ q,   // [NTOK][3072] rope-applied
  const unsigned short* __restrict__ kv,  // [NTOK][4096]
  const unsigned short* __restrict__ kr,  // [NTOK][64] roped
  const unsigned short* __restrict__ vT,  // [32][128][S]
  unsigned short* __restrict__ attn)      // [NTOK][2048]
{
  __shared__ unsigned short Ksn[2][32*128];  // 8 KB each
  __shared__ unsigned short Ksr[2][32*64];   // 4 KB each
  __shared__ unsigned short Vs [2][128*32];  // 8 KB each
  __shared__ unsigned short Ps [4*32*36];    // per-wave 32 rows x 72 B
  const int tid = threadIdx.x, wave = tid>>6, lane = tid&63;
  const int lo = lane&31, hi = lane>>5;
  const int lin = blockIdx.x;
  const int bh = (lin&7) + 8*((lin>>3)&3);
  const int qt = NQT2-1 - (lin>>5);
  const int b = bh>>4, h = bh&15;
  const float kmul = 1.44269504f * 0.07216878364f; // log2e / sqrt(192)

  const int rK = tid>>4, cK = (tid&15) ^ (rK&7);
  const int rR = tid>>3, cR = (tid&7) ^ (rR&7);
  const int rV = tid>>2, cV = (tid&3) ^ (rV&3);
  const unsigned short* pKn0 = kv + (size_t)(b*SS + rK)*KVD + h*(DN+DV) + cK*8;
  const unsigned short* pKn1 = pKn0 + (size_t)16*KVD;
  const unsigned short* pKr  = kr + (size_t)(b*SS + rR)*64 + cR*8;
  const unsigned short* pV0  = vT + ((size_t)bh*DV + rV)*SS + cV*8;
  const unsigned short* pV1  = pV0 + (size_t)64*SS;

#define STAGE_ATTN(bufi) do {                                                 \
    GLOAD16(pKn0, (char*)Ksn[bufi] +        wave*1024);                       \
    GLOAD16(pKn1, (char*)Ksn[bufi] + 4096 + wave*1024);                       \
    GLOAD16(pKr,  (char*)Ksr[bufi] +        wave*1024);                       \
    GLOAD16(pV0,  (char*)Vs[bufi]  +        wave*1024);                       \
    GLOAD16(pV1,  (char*)Vs[bufi]  + 4096 + wave*1024);                       \
    pKn0 += 32*KVD; pKn1 += 32*KVD; pKr += 32*64; pV0 += 32; pV1 += 32;       \
  } while(0)

  const int qw = qt*128 + wave*32;
  const int myq = qw + lo;
  bf16x8 qf[12];
  {
    const unsigned short* qrow = q + (size_t)(b*SS + myq)*QD + h*(DN+DR);
    #pragma unroll
    for (int c=0;c<12;c++) qf[c] = *(const bf16x8*)(qrow + c*16 + hi*8);
  }
  f32x16 oacc[4] = {};
  float m = -1e30f, lsum = 0.f;
  const int nkt = 4*qt + 4;

  STAGE_ATTN(0);
  asm volatile("s_waitcnt vmcnt(0)" ::: "memory");
  __builtin_amdgcn_s_barrier();
  int cur = 0;
  for (int kt = 0; kt < nkt; kt++){
    if (kt+1 < nkt) STAGE_ATTN(cur^1);
    // ---- QK^T: S^T[key=32][q=32], A = K-tile rows, B = Q regs ----
    f32x16 sacc = {};
    #pragma unroll
    for (int ck=0;ck<8;ck++){
      bf16x8 kf = *(const bf16x8*)((char*)Ksn[cur] + lo*256 + ((((ck*2+hi)^(lo&7)))<<4));
      sacc = __builtin_amdgcn_mfma_f32_32x32x16_bf16(kf, qf[ck], sacc, 0,0,0);
    }
    #pragma unroll
    for (int ck=0;ck<4;ck++){
      bf16x8 kf = *(const bf16x8*)((char*)Ksr[cur] + lo*128 + ((((ck*2+hi)^(lo&7)))<<4));
      sacc = __builtin_amdgcn_mfma_f32_32x32x16_bf16(kf, qf[8+ck], sacc, 0,0,0);
    }
    // ---- online softmax: key-row(r) = (r&3)+8*(r>>2)+4*hi, q-col = lo ----
    float s[16]; float pmax = -1e30f;
    if (kt*32 + 31 <= qw){
      #pragma unroll
      for (int r=0;r<16;r++){ float v = sacc[r]*kmul; s[r]=v; pmax=fmaxf(pmax,v); }
    } else {
      #pragma unroll
      for (int r=0;r<16;r++){
        int kpos = kt*32 + (r&3) + 8*(r>>2) + 4*hi;
        float v = (kpos <= myq) ? sacc[r]*kmul : -1e30f;
        s[r]=v; pmax=fmaxf(pmax,v);
      }
    }
    pmax = fmaxf(pmax, __shfl_xor(pmax, 32, 64));
    if (!__all(pmax <= m + 8.f)){   // defer-max
      float mnew = fmaxf(m, pmax);
      float alpha = __builtin_amdgcn_exp2f(m - mnew);
      m = mnew; lsum *= alpha;
      #pragma unroll
      for (int dt=0;dt<4;dt++)
        #pragma unroll
        for (int r=0;r<16;r++) oacc[dt][r] *= alpha;
    }
    float psum = 0.f;
    #pragma unroll
    for (int r=0;r<16;r++){ s[r] = __builtin_amdgcn_exp2f(s[r] - m); psum += s[r]; }
    psum += __shfl_xor(psum, 32, 64);
    lsum += psum;
    // ---- P -> per-wave padded LDS tile, then B-fragments ----
    unsigned short* Pw = Ps + wave*32*36;
    #pragma unroll
    for (int rg=0; rg<4; rg++){
      uint2 pk = { cvt_pk_bf16(s[rg*4+0], s[rg*4+1]),
                   cvt_pk_bf16(s[rg*4+2], s[rg*4+3]) };
      *(uint2*)((char*)Pw + lo*72 + rg*16 + hi*8) = pk;
    }
    bf16x8 pf[2];
    #pragma unroll
    for (int j=0;j<2;j++){
      uint2 a0 = *(const uint2*)((char*)Pw + lo*72 + (2*j+hi)*16);
      uint2 a1 = *(const uint2*)((char*)Pw + lo*72 + (2*j+hi)*16 + 8);
      u32x4 pk4 = { a0.x, a0.y, a1.x, a1.y };
      pf[j] = __builtin_bit_cast(bf16x8, pk4);
    }
    // ---- PV: O[d=32][q=32] per d-tile, A = V^T rows, B = pf ----
    #pragma unroll
    for (int dt=0; dt<4; dt++){
      const int row = dt*32 + lo;
      #pragma unroll
      for (int j=0;j<2;j++){
        bf16x8 vf = *(const bf16x8*)((char*)Vs[cur] + row*64 + ((((j*2+hi)^(lo&3)))<<4));
        oacc[dt] = __builtin_amdgcn_mfma_f32_32x32x16_bf16(vf, pf[j], oacc[dt], 0,0,0);
      }
    }
    asm volatile("s_waitcnt vmcnt(0)" ::: "memory");
    __builtin_amdgcn_s_barrier();
    cur ^= 1;
  }
  // ---- epilogue: O rows d = (r&3)+8*(r>>2)+4*hi+32*dt, col q = lo ----
  float inv = 1.f / lsum;
  unsigned short* orow = attn + (size_t)(b*SS + myq)*2048 + h*DV;
  #pragma unroll
  for (int dt=0; dt<4; dt++){
    #pragma unroll
    for (int rq=0; rq<4; rq++){
      int dbase = dt*32 + rq*8 + hi*4;
      uint2 o = { cvt_pk_bf16(oacc[dt][rq*4+0]*inv, oacc[dt][rq*4+1]*inv),
                  cvt_pk_bf16(oacc[dt][rq*4+2]*inv, oacc[dt][rq*4+3]*inv) };
      *(uint2*)(orow + dbase) = o;
    }
  }
#undef STAGE_ATTN
}

// ---------- launch ----------
extern "C" void kernel_launch(void* const* d_in, const int* in_sizes, int n_in,
                              void* d_out, int out_size, void* d_ws, size_t ws_size,
                              hipStream_t stream){
  const float* X    = (const float*)d_in[0];
  const float* Wqd  = (const float*)d_in[2];
  const float* bqd  = (const float*)d_in[3];
  const float* Wqu  = (const float*)d_in[4];
  const float* bqu  = (const float*)d_in[5];
  const float* Wkvd = (const float*)d_in[6];
  const float* bkvd = (const float*)d_in[7];
  const float* Wkvu = (const float*)d_in[8];
  const float* bkvu = (const float*)d_in[9];
  const float* Wo   = (const float*)d_in[10];
  const float* bo   = (const float*)d_in[11];
  float* out = (float*)d_out;

  char* ws = (char*)d_ws;
  // workspace layout (bytes); attn output overlays Xb (dead after G1G3)
  unsigned short* Xb    = (unsigned short*)(ws + 0);          // 16,777,216
  unsigned short* attnb = (unsigned short*)(ws + 0);
  char*           arena = ws + 16777216;                      // weight arena
  unsigned short* Wt1 = (unsigned short*)(arena);             // 1536x2048x2 = 6,291,456
  unsigned short* Wt3 = (unsigned short*)(arena + 6291456);   // 640x2048x2  = 2,621,440
  unsigned short* Wt2 = (unsigned short*)(arena);             // 3072x1536x2 = 9,437,184
  unsigned short* Wt4 = (unsigned short*)(arena + 9437184);   // 4096x512x2  = 4,194,304
  unsigned short* Wt5 = (unsigned short*)(arena);             // 2048x2048x2 = 8,388,608
  unsigned short* cq   = (unsigned short*)(ws + 31457280);    // 12,582,912
  unsigned short* qtmp = (unsigned short*)(ws + 44040192);    // 25,165,824
  unsigned short* ckv  = (unsigned short*)(ws + 69206016);    //  4,718,592
  unsigned short* kvt  = (unsigned short*)(ws + 73924608);    // 33,554,432
  unsigned short* kr   = (unsigned short*)(ws + 107479040);   //    524,288
  unsigned short* vT   = (unsigned short*)(ws + 108003328);   // 16,777,216  (end 124,780,544)

  // 1. fused: X->bf16 + Wqd^T + Wkvd^T (independent, one dispatch)
  prep_down<<<dim3(12544), 256, 0, stream>>>(X, Xb, Wqd, Wt1, Wkvd, Wt3);
  // 2. fused G1+G3
  gemm_bt_dual<<<dim3(QLR/128 + 640/128, NTOK/128), 256, 0, stream>>>(
      Xb, HID, Wt1, bqd, cq, QLR, QLR, HID,
      Xb, HID, Wt3, bkvd, ckv, CKVD, CKVD, HID, QLR/128);
  // 3. norms + k rope (fused)
  norms_fused<<<dim3(2*NTOK + NTOK*32/256), 256, 0, stream>>>(cq, ckv, kr);
  // 4. fused: Wqu^T + Wkvu^T ; fused G2+G4
  prep_up<<<dim3(6656), 256, 0, stream>>>(Wqu, Wt2, Wkvu, Wt4);
  gemm_bt_dual<<<dim3(QD/128 + KVD/128, NTOK/128), 256, 0, stream>>>(
      cq, QLR, Wt2, bqu, qtmp, QD, QD, QLR,
      ckv + DR, CKVD, Wt4, bkvu, kvt, KVD, KVD, KVLR, QD/128);
  // 5. q rope + V^T + Wo^T (fused; arena dead after G2G4)
  ropeq_vt_wo_fused<<<dim3(8192 + 8192 + 4096), 256, 0, stream>>>(qtmp, kvt, vT, Wo, Wt5);
  // 6. attention (512 blocks, 32x32 MFMA, XCD-grouped, big-qt first)
  attn_kernel<<<dim3(NQT2 * BB*NH), 256, 0, stream>>>(qtmp, kvt, kr, vT, attnb);
  // 7. GEMM5 -> out (f32)
  gemm_bt<true><<<dim3(HID/128, NTOK/128), 256, 0, stream>>>(attnb, HID, Wt5, bo, out, HID, HID, HID);
}